// Round 1
// baseline (449.804 us; speedup 1.0000x reference)
//
#include <hip/hip_runtime.h>
#include <hip/hip_bf16.h>
#include <stdint.h>

// Problem constants
#define Bb 4
#define Tt 1024
#define Hh 16
#define HD 64
#define C3 3072
#define WIN 64  // MEMORY

typedef __bf16 bf16x8 __attribute__((ext_vector_type(8)));
typedef float f32x4 __attribute__((ext_vector_type(4)));

#define MFMA16(a, b, c) __builtin_amdgcn_mfma_f32_16x16x32_bf16((a), (b), (c), 0, 0, 0)

static __device__ __forceinline__ unsigned short f2bf(float f) {
  union { float f; unsigned u; } v; v.f = f;
  unsigned r = (v.u + 0x7FFFu + ((v.u >> 16) & 1u)) >> 16;
  return (unsigned short)r;
}
static __device__ __forceinline__ float bf2f(unsigned short h) {
  union { unsigned u; float f; } v; v.u = ((unsigned)h) << 16;
  return v.f;
}

// ---------------- fp32 -> bf16 convert (vectorized) ----------------
__global__ __launch_bounds__(256) void k_convert(const float* __restrict__ in,
                                                 unsigned short* __restrict__ out, int n4) {
  int i = blockIdx.x * 256 + threadIdx.x;
  if (i >= n4) return;
  float4 v = ((const float4*)in)[i];
  ushort4 o;
  o.x = f2bf(v.x); o.y = f2bf(v.y); o.z = f2bf(v.z); o.w = f2bf(v.w);
  ((ushort4*)out)[i] = o;
}

// ------------- transpose + convert: W [K][N] fp32 -> Wt [N][K] bf16 -------------
__global__ __launch_bounds__(256) void k_transconv(const float* __restrict__ Win,
                                                   unsigned short* __restrict__ Wt,
                                                   int K, int N) {
  __shared__ float tile[32][33];
  int n0 = blockIdx.x * 32, k0 = blockIdx.y * 32;
  int tx = threadIdx.x & 31, ty = threadIdx.x >> 5;
  for (int r = ty; r < 32; r += 8)
    tile[r][tx] = Win[(size_t)(k0 + r) * N + n0 + tx];
  __syncthreads();
  for (int r = ty; r < 32; r += 8)
    Wt[(size_t)(n0 + r) * K + k0 + tx] = f2bf(tile[tx][r]);
}

// ------------- bf16 GEMM: C[M][N] = A[M][K] * Bt[N][K]^T  (m97-style 128x128 tile) -------------
template <int BF16_OUT, int SCALEQ>
__global__ __launch_bounds__(256) void k_gemm_bt(const unsigned short* __restrict__ A,
                                                 const unsigned short* __restrict__ Bt,
                                                 void* __restrict__ Cv, int M, int N, int K) {
  __shared__ unsigned short lds[2 * 128 * 32];
  unsigned short* as_ = lds;
  unsigned short* bs_ = lds + 128 * 32;
  const int tid = threadIdx.x;
  const int m0 = blockIdx.x * 128, n0 = blockIdx.y * 128;
  const int w = tid >> 6, lane = tid & 63;
  const int wm = (w >> 1) * 64, wn = (w & 1) * 64;
  const int lrow = lane & 15, lk = lane >> 4;

  f32x4 z = {0.f, 0.f, 0.f, 0.f};
  f32x4 acc[4][4];
#pragma unroll
  for (int i = 0; i < 4; ++i)
#pragma unroll
    for (int j = 0; j < 4; ++j) acc[i][j] = z;

  const int nk = K >> 5;
  for (int kt = 0; kt < nk; ++kt) {
    const int k0 = kt << 5;
    __syncthreads();
#pragma unroll
    for (int p = 0; p < 2; ++p) {
      int seg = tid + p * 256;
      int row = seg >> 2, ks = (seg & 3) << 3;
      __builtin_amdgcn_global_load_lds(
          (__attribute__((address_space(1))) void*)(A + (size_t)(m0 + row) * K + k0 + ks),
          (__attribute__((address_space(3))) void*)(as_ + seg * 8), 16, 0, 0);
      __builtin_amdgcn_global_load_lds(
          (__attribute__((address_space(1))) void*)(Bt + (size_t)(n0 + row) * K + k0 + ks),
          (__attribute__((address_space(3))) void*)(bs_ + seg * 8), 16, 0, 0);
    }
    __syncthreads();
    bf16x8 af[4], bfr[4];
#pragma unroll
    for (int f = 0; f < 4; ++f) {
      af[f] = *(const bf16x8*)(as_ + (wm + f * 16 + lrow) * 32 + lk * 8);
      bfr[f] = *(const bf16x8*)(bs_ + (wn + f * 16 + lrow) * 32 + lk * 8);
    }
#pragma unroll
    for (int i = 0; i < 4; ++i)
#pragma unroll
      for (int j = 0; j < 4; ++j) acc[i][j] = MFMA16(af[i], bfr[j], acc[i][j]);
  }
  // epilogue: D row = (lane>>4)*4+r, col = lane&15
  const int r0 = lk * 4;
#pragma unroll
  for (int i = 0; i < 4; ++i)
#pragma unroll
    for (int j = 0; j < 4; ++j)
#pragma unroll
      for (int r = 0; r < 4; ++r) {
        int gm = m0 + wm + i * 16 + r0 + r;
        int gn = n0 + wn + j * 16 + lrow;
        float v = acc[i][j][r];
        if (SCALEQ) {
          if (gn < 1024) v *= 0.125f;  // fold 1/sqrt(hd) into q
        }
        if (BF16_OUT)
          ((unsigned short*)Cv)[(size_t)gm * N + gn] = f2bf(v);
        else
          ((float*)Cv)[(size_t)gm * N + gn] = v;
      }
}

// ------------- causal softmax row stats: m and 1/l per (b,h,i) -------------
// qkv layout [B][T][3C]; q at +0 (pre-scaled), k at +1024, v at +2048 within row.
__global__ __launch_bounds__(256) void k_stats(const unsigned short* __restrict__ qkv,
                                               float2* __restrict__ stats) {
  int blk = blockIdx.x;
  int it = blk & 15, h = (blk >> 4) & 15, b = blk >> 8;
  int w = threadIdx.x >> 6, lane = threadIdx.x & 63;
  int lrow = lane & 15, lk = lane >> 4;
  int ibase = it * 64 + w * 16;

  const size_t qrow = ((size_t)(b * Tt + ibase + lrow)) * C3 + h * 64 + lk * 8;
  bf16x8 qf0 = *(const bf16x8*)(qkv + qrow);
  bf16x8 qf1 = *(const bf16x8*)(qkv + qrow + 32);

  float m[4] = {-1e30f, -1e30f, -1e30f, -1e30f};
  float l[4] = {0.f, 0.f, 0.f, 0.f};
  const int jtmax = ibase >> 4;
  for (int jt = 0; jt <= jtmax; ++jt) {
    const size_t krow = ((size_t)(b * Tt + jt * 16 + lrow)) * C3 + 1024 + h * 64 + lk * 8;
    bf16x8 kf0 = *(const bf16x8*)(qkv + krow);
    bf16x8 kf1 = *(const bf16x8*)(qkv + krow + 32);
    f32x4 s = {0.f, 0.f, 0.f, 0.f};
    s = MFMA16(qf0, kf0, s);
    s = MFMA16(qf1, kf1, s);
    const int jg = jt * 16 + lrow;
#pragma unroll
    for (int r = 0; r < 4; ++r) {
      int ig = ibase + lk * 4 + r;
      float sv = (jg <= ig) ? s[r] : -1e30f;
      float tm = sv;
      tm = fmaxf(tm, __shfl_xor(tm, 1));
      tm = fmaxf(tm, __shfl_xor(tm, 2));
      tm = fmaxf(tm, __shfl_xor(tm, 4));
      tm = fmaxf(tm, __shfl_xor(tm, 8));
      float mnew = fmaxf(m[r], tm);
      float p = __expf(sv - mnew);
      float ts = p;
      ts += __shfl_xor(ts, 1);
      ts += __shfl_xor(ts, 2);
      ts += __shfl_xor(ts, 4);
      ts += __shfl_xor(ts, 8);
      l[r] = l[r] * __expf(m[r] - mnew) + ts;
      m[r] = mnew;
    }
  }
  if (lrow == 0) {
#pragma unroll
    for (int r = 0; r < 4; ++r) {
      int ig = ibase + lk * 4 + r;
      stats[((size_t)(b * Hh + h)) * Tt + ig] = make_float2(m[r], 1.0f / l[r]);
    }
  }
}

// ------------- att (full causal probs, all 4 batches) + att_std, per 32x32 tile -------------
__global__ __launch_bounds__(256) void k_att(const unsigned short* __restrict__ qkv,
                                             const float2* __restrict__ stats,
                                             float* __restrict__ att, float* __restrict__ astd) {
  const int tj = blockIdx.x, ti = blockIdx.y, h = blockIdx.z;
  const int i0 = ti * 32, j0 = tj * 32;
  const int tid = threadIdx.x;

  if (tj > ti) {  // fully masked tile: stream zeros
    float4 z4 = make_float4(0.f, 0.f, 0.f, 0.f);
    for (int s = tid; s < 1024; s += 256) {
      int b = s >> 8, r = (s >> 3) & 31, c = s & 7;
      ((float4*)(att + (((size_t)(b * Hh + h)) * Tt + i0 + r) * Tt + j0))[c] = z4;
    }
    {
      int r = tid >> 3, c = tid & 7;
      ((float4*)(astd + ((size_t)h * Tt + i0 + r) * Tt + j0))[c] = z4;
    }
    return;
  }

  const int w = tid >> 6, lane = tid & 63;
  const int qi = (w >> 1) * 16, qj = (w & 1) * 16;
  const int lrow = lane & 15, lk = lane >> 4;
  const int ibase = i0 + qi, jbase = j0 + qj;
  const int jg = jbase + lrow;

  float s1[4] = {0.f, 0.f, 0.f, 0.f}, s2[4] = {0.f, 0.f, 0.f, 0.f};
#pragma unroll
  for (int b = 0; b < Bb; ++b) {
    const size_t qrow = ((size_t)(b * Tt + ibase + lrow)) * C3 + h * 64 + lk * 8;
    const size_t krow = ((size_t)(b * Tt + jbase + lrow)) * C3 + 1024 + h * 64 + lk * 8;
    bf16x8 qf0 = *(const bf16x8*)(qkv + qrow);
    bf16x8 qf1 = *(const bf16x8*)(qkv + qrow + 32);
    bf16x8 kf0 = *(const bf16x8*)(qkv + krow);
    bf16x8 kf1 = *(const bf16x8*)(qkv + krow + 32);
    f32x4 s = {0.f, 0.f, 0.f, 0.f};
    s = MFMA16(qf0, kf0, s);
    s = MFMA16(qf1, kf1, s);
#pragma unroll
    for (int r = 0; r < 4; ++r) {
      int ig = ibase + lk * 4 + r;
      float2 st = stats[((size_t)(b * Hh + h)) * Tt + ig];
      float p = (jg <= ig) ? __expf(s[r] - st.x) * st.y : 0.0f;
      att[(((size_t)(b * Hh + h)) * Tt + ig) * Tt + jg] = p;
      s1[r] += p;
      s2[r] += p * p;
    }
  }
#pragma unroll
  for (int r = 0; r < 4; ++r) {
    int ig = ibase + lk * 4 + r;
    float mean = s1[r] * 0.25f;
    float var = (s2[r] - 4.0f * mean * mean) * (1.0f / 3.0f);
    astd[((size_t)h * Tt + ig) * Tt + jg] = sqrtf(fmaxf(var, 0.0f));
  }
}

// ------------- banded (window=64) softmax @ V  ->  y_heads bf16 [B][T][C] -------------
__global__ __launch_bounds__(256) void k_bandy(const unsigned short* __restrict__ qkv,
                                               unsigned short* __restrict__ yh) {
  __shared__ unsigned short qls[64 * 66];
  __shared__ unsigned short kls[128 * 66];
  __shared__ unsigned short vls[128 * 66];
  __shared__ float pls[4][80];

  int blk = blockIdx.x;
  int it = blk & 15, h = (blk >> 4) & 15, b = blk >> 8;
  int i0 = it * 64;
  int jb = i0 - 64;
  int tid = threadIdx.x;

  // stage q rows [i0, i0+63], k/v rows [i0-64, i0+63] (row<0 -> zeros)
  for (int r = tid; r < 320; r += 256) {
    unsigned short* dst;
    int grow, sel;
    if (r < 64) { dst = qls + r * 66; grow = i0 + r; sel = 0; }
    else if (r < 192) { dst = kls + (r - 64) * 66; grow = jb + (r - 64); sel = 1; }
    else { dst = vls + (r - 192) * 66; grow = jb + (r - 192); sel = 2; }
    if (grow < 0) {
      for (int t = 0; t < 32; ++t) ((unsigned*)dst)[t] = 0u;
    } else {
      const unsigned* src = (const unsigned*)(qkv + ((size_t)(b * Tt + grow)) * C3 + sel * 1024 + h * 64);
      for (int t = 0; t < 32; ++t) ((unsigned*)dst)[t] = src[t];
    }
  }
  __syncthreads();

  const int w = tid >> 6, lane = tid & 63;
  for (int rr = 0; rr < 16; ++rr) {
    const int i = i0 + (w << 4) + rr;
    const int io = i - i0;
    const int ja = i - 64 + lane;           // key for this lane
    const unsigned* qrow = (const unsigned*)(qls + io * 66);
    const unsigned* krow = (const unsigned*)(kls + (size_t)(io + lane) * 66);
    const unsigned* kerow = (const unsigned*)(kls + (size_t)(io + 64) * 66);  // key j=i
    float sa = 0.f, se = 0.f;
#pragma unroll 8
    for (int t = 0; t < 32; ++t) {
      unsigned qq = qrow[t];
      float q0 = bf2f((unsigned short)qq), q1 = bf2f((unsigned short)(qq >> 16));
      unsigned kk = krow[t];
      sa = fmaf(q0, bf2f((unsigned short)kk), sa);
      sa = fmaf(q1, bf2f((unsigned short)(kk >> 16)), sa);
      unsigned ke = kerow[t];
      se = fmaf(q0, bf2f((unsigned short)ke), se);
      se = fmaf(q1, bf2f((unsigned short)(ke >> 16)), se);
    }
    if (ja < 0) sa = -1e30f;
    float m = sa;
    m = fmaxf(m, __shfl_xor(m, 1));
    m = fmaxf(m, __shfl_xor(m, 2));
    m = fmaxf(m, __shfl_xor(m, 4));
    m = fmaxf(m, __shfl_xor(m, 8));
    m = fmaxf(m, __shfl_xor(m, 16));
    m = fmaxf(m, __shfl_xor(m, 32));
    m = fmaxf(m, se);  // se identical on all lanes
    float pa = __expf(sa - m);
    float pe = __expf(se - m);
    float sum = pa;
    sum += __shfl_xor(sum, 1);
    sum += __shfl_xor(sum, 2);
    sum += __shfl_xor(sum, 4);
    sum += __shfl_xor(sum, 8);
    sum += __shfl_xor(sum, 16);
    sum += __shfl_xor(sum, 32);
    sum += pe;
    float rl = 1.0f / sum;
    pls[w][lane] = pa * rl;
    if (lane == 0) pls[w][64] = pe * rl;
    // PV: lane owns output dim d = lane; keys are idx = io + t, t=0..64
    float y = 0.f;
#pragma unroll 4
    for (int t = 0; t <= 64; ++t)
      y = fmaf(pls[w][t], bf2f(vls[(size_t)(io + t) * 66 + lane]), y);
    yh[((size_t)(b * Tt + i)) * 1024 + h * 64 + lane] = f2bf(y);
  }
}

// ============================ host ============================
extern "C" void kernel_launch(void* const* d_in, const int* in_sizes, int n_in,
                              void* d_out, int out_size, void* d_ws, size_t ws_size,
                              hipStream_t stream) {
  const float* x = (const float*)d_in[0];
  const float* Wa = (const float*)d_in[1];
  const float* Wp = (const float*)d_in[2];

  float* out = (float*)d_out;
  float* y_out = out;                               // [4,1024,1024]
  float* att = out + (size_t)4194304;               // [4,16,1024,1024]
  float* astd = out + (size_t)71303168;             // [16,1024,1024]

  // d_ws scratch: qkv bf16 | y_heads bf16 | WtP bf16 | stats   (36.2 MB)
  char* ws = (char*)d_ws;
  unsigned short* qkv = (unsigned short*)ws;                 // 25165824 B
  unsigned short* yh = (unsigned short*)(ws + 25165824);     // 8388608 B
  unsigned short* WtP = (unsigned short*)(ws + 33554432);    // 2097152 B
  float2* stats = (float2*)(ws + 35651584);                  // 524288 B

  // park WtA + x_bf16 inside the y output region (dead until final GEMM writes y)
  char* yreg = (char*)d_out;
  unsigned short* WtA = (unsigned short*)yreg;               // 6291456 B
  unsigned short* xbf = (unsigned short*)(yreg + 6291456);   // 8388608 B

  k_convert<<<4096, 256, 0, stream>>>(x, xbf, 1048576);
  k_transconv<<<dim3(96, 32), 256, 0, stream>>>(Wa, WtA, 1024, 3072);
  k_transconv<<<dim3(32, 32), 256, 0, stream>>>(Wp, WtP, 1024, 1024);
  // qkv = x @ W_attn  (q pre-scaled by 1/8), bf16 out
  k_gemm_bt<1, 1><<<dim3(32, 24), 256, 0, stream>>>(xbf, WtA, qkv, 4096, 3072, 1024);
  k_stats<<<1024, 256, 0, stream>>>(qkv, stats);
  k_att<<<dim3(32, 32, 16), 256, 0, stream>>>(qkv, stats, att, astd);
  k_bandy<<<1024, 256, 0, stream>>>(qkv, yh);
  // y = y_heads @ W_proj, fp32 out (overwrites the WtA/xbf scratch in-place)
  k_gemm_bt<0, 0><<<dim3(32, 8), 256, 0, stream>>>(yh, WtP, y_out, 4096, 1024, 1024);
}

// Round 3
// 400.603 us; speedup vs baseline: 1.1228x; 1.1228x over previous
//
#include <hip/hip_runtime.h>
#include <hip/hip_bf16.h>
#include <stdint.h>

// Problem constants
#define Bb 4
#define Tt 1024
#define Hh 16
#define HD 64
#define C3 3072
#define WIN 64  // MEMORY

typedef __bf16 bf16x8 __attribute__((ext_vector_type(8)));
typedef float f32x4 __attribute__((ext_vector_type(4)));

#define MFMA16(a, b, c) __builtin_amdgcn_mfma_f32_16x16x32_bf16((a), (b), (c), 0, 0, 0)

static __device__ __forceinline__ unsigned short f2bf(float f) {
  union { float f; unsigned u; } v; v.f = f;
  unsigned r = (v.u + 0x7FFFu + ((v.u >> 16) & 1u)) >> 16;
  return (unsigned short)r;
}
static __device__ __forceinline__ float bf2f(unsigned short h) {
  union { unsigned u; float f; } v; v.u = ((unsigned)h) << 16;
  return v.f;
}

// ---------------- fp32 -> bf16 convert (vectorized) ----------------
__global__ __launch_bounds__(256) void k_convert(const float* __restrict__ in,
                                                 unsigned short* __restrict__ out, int n4) {
  int i = blockIdx.x * 256 + threadIdx.x;
  if (i >= n4) return;
  float4 v = ((const float4*)in)[i];
  ushort4 o;
  o.x = f2bf(v.x); o.y = f2bf(v.y); o.z = f2bf(v.z); o.w = f2bf(v.w);
  ((ushort4*)out)[i] = o;
}

// ------------- transpose + convert: W [K][N] fp32 -> Wt [N][K] bf16 -------------
__global__ __launch_bounds__(256) void k_transconv(const float* __restrict__ Win,
                                                   unsigned short* __restrict__ Wt,
                                                   int K, int N) {
  __shared__ float tile[32][33];
  int n0 = blockIdx.x * 32, k0 = blockIdx.y * 32;
  int tx = threadIdx.x & 31, ty = threadIdx.x >> 5;
  for (int r = ty; r < 32; r += 8)
    tile[r][tx] = Win[(size_t)(k0 + r) * N + n0 + tx];
  __syncthreads();
  for (int r = ty; r < 32; r += 8)
    Wt[(size_t)(n0 + r) * K + k0 + tx] = f2bf(tile[tx][r]);
}

// ------------- bf16 GEMM: C[M][N] = A[M][K] * Bt[N][K]^T  (m97-style 128x128 tile) -------------
template <int BF16_OUT, int SCALEQ>
__global__ __launch_bounds__(256) void k_gemm_bt(const unsigned short* __restrict__ A,
                                                 const unsigned short* __restrict__ Bt,
                                                 void* __restrict__ Cv, int M, int N, int K) {
  __shared__ unsigned short lds[2 * 128 * 32];
  unsigned short* as_ = lds;
  unsigned short* bs_ = lds + 128 * 32;
  const int tid = threadIdx.x;
  const int m0 = blockIdx.x * 128, n0 = blockIdx.y * 128;
  const int w = tid >> 6, lane = tid & 63;
  const int wm = (w >> 1) * 64, wn = (w & 1) * 64;
  const int lrow = lane & 15, lk = lane >> 4;

  f32x4 z = {0.f, 0.f, 0.f, 0.f};
  f32x4 acc[4][4];
#pragma unroll
  for (int i = 0; i < 4; ++i)
#pragma unroll
    for (int j = 0; j < 4; ++j) acc[i][j] = z;

  const int nk = K >> 5;
  for (int kt = 0; kt < nk; ++kt) {
    const int k0 = kt << 5;
    __syncthreads();
#pragma unroll
    for (int p = 0; p < 2; ++p) {
      int seg = tid + p * 256;
      int row = seg >> 2, ks = (seg & 3) << 3;
      __builtin_amdgcn_global_load_lds(
          (__attribute__((address_space(1))) void*)(A + (size_t)(m0 + row) * K + k0 + ks),
          (__attribute__((address_space(3))) void*)(as_ + seg * 8), 16, 0, 0);
      __builtin_amdgcn_global_load_lds(
          (__attribute__((address_space(1))) void*)(Bt + (size_t)(n0 + row) * K + k0 + ks),
          (__attribute__((address_space(3))) void*)(bs_ + seg * 8), 16, 0, 0);
    }
    __syncthreads();
    bf16x8 af[4], bfr[4];
#pragma unroll
    for (int f = 0; f < 4; ++f) {
      af[f] = *(const bf16x8*)(as_ + (wm + f * 16 + lrow) * 32 + lk * 8);
      bfr[f] = *(const bf16x8*)(bs_ + (wn + f * 16 + lrow) * 32 + lk * 8);
    }
#pragma unroll
    for (int i = 0; i < 4; ++i)
#pragma unroll
      for (int j = 0; j < 4; ++j) acc[i][j] = MFMA16(af[i], bfr[j], acc[i][j]);
  }
  // epilogue: D row = (lane>>4)*4+r, col = lane&15
  const int r0 = lk * 4;
#pragma unroll
  for (int i = 0; i < 4; ++i)
#pragma unroll
    for (int j = 0; j < 4; ++j)
#pragma unroll
      for (int r = 0; r < 4; ++r) {
        int gm = m0 + wm + i * 16 + r0 + r;
        int gn = n0 + wn + j * 16 + lrow;
        float v = acc[i][j][r];
        if (SCALEQ) {
          if (gn < 1024) v *= 0.125f;  // fold 1/sqrt(hd) into q
        }
        if (BF16_OUT)
          ((unsigned short*)Cv)[(size_t)gm * N + gn] = f2bf(v);
        else
          ((float*)Cv)[(size_t)gm * N + gn] = v;
      }
}

// ------------- causal softmax row stats: m and 1/l per (b,h,i) -------------
// (round-1 verbatim, known-good)
__global__ __launch_bounds__(256) void k_stats(const unsigned short* __restrict__ qkv,
                                               float2* __restrict__ stats) {
  int blk = blockIdx.x;
  int it = blk & 15, h = (blk >> 4) & 15, b = blk >> 8;
  int w = threadIdx.x >> 6, lane = threadIdx.x & 63;
  int lrow = lane & 15, lk = lane >> 4;
  int ibase = it * 64 + w * 16;

  const size_t qrow = ((size_t)(b * Tt + ibase + lrow)) * C3 + h * 64 + lk * 8;
  bf16x8 qf0 = *(const bf16x8*)(qkv + qrow);
  bf16x8 qf1 = *(const bf16x8*)(qkv + qrow + 32);

  float m[4] = {-1e30f, -1e30f, -1e30f, -1e30f};
  float l[4] = {0.f, 0.f, 0.f, 0.f};
  const int jtmax = ibase >> 4;
  for (int jt = 0; jt <= jtmax; ++jt) {
    const size_t krow = ((size_t)(b * Tt + jt * 16 + lrow)) * C3 + 1024 + h * 64 + lk * 8;
    bf16x8 kf0 = *(const bf16x8*)(qkv + krow);
    bf16x8 kf1 = *(const bf16x8*)(qkv + krow + 32);
    f32x4 s = {0.f, 0.f, 0.f, 0.f};
    s = MFMA16(qf0, kf0, s);
    s = MFMA16(qf1, kf1, s);
    const int jg = jt * 16 + lrow;
#pragma unroll
    for (int r = 0; r < 4; ++r) {
      int ig = ibase + lk * 4 + r;
      float sv = (jg <= ig) ? s[r] : -1e30f;
      float tm = sv;
      tm = fmaxf(tm, __shfl_xor(tm, 1));
      tm = fmaxf(tm, __shfl_xor(tm, 2));
      tm = fmaxf(tm, __shfl_xor(tm, 4));
      tm = fmaxf(tm, __shfl_xor(tm, 8));
      float mnew = fmaxf(m[r], tm);
      float p = __expf(sv - mnew);
      float ts = p;
      ts += __shfl_xor(ts, 1);
      ts += __shfl_xor(ts, 2);
      ts += __shfl_xor(ts, 4);
      ts += __shfl_xor(ts, 8);
      l[r] = l[r] * __expf(m[r] - mnew) + ts;
      m[r] = mnew;
    }
  }
  if (lrow == 0) {
#pragma unroll
    for (int r = 0; r < 4; ++r) {
      int ig = ibase + lk * 4 + r;
      stats[((size_t)(b * Hh + h)) * Tt + ig] = make_float2(m[r], 1.0f / l[r]);
    }
  }
}

// ------------- att (full causal probs) + att_std, per 32x32 tile -------------
// wave = batch; probabilities staged in LDS; float4 stores for att and astd.
__global__ __launch_bounds__(256) void k_att(const unsigned short* __restrict__ qkv,
                                             const float2* __restrict__ stats,
                                             float* __restrict__ att, float* __restrict__ astd) {
  const int tj = blockIdx.x, ti = blockIdx.y, h = blockIdx.z;
  const int i0 = ti * 32, j0 = tj * 32;
  const int tid = threadIdx.x;

  if (tj > ti) {  // fully masked tile: stream zeros
    float4 z4 = make_float4(0.f, 0.f, 0.f, 0.f);
    for (int s = tid; s < 1024; s += 256) {
      int b = s >> 8, r = (s >> 3) & 31, c = s & 7;
      ((float4*)(att + (((size_t)(b * Hh + h)) * Tt + i0 + r) * Tt + j0))[c] = z4;
    }
    {
      int r = tid >> 3, c = tid & 7;
      ((float4*)(astd + ((size_t)h * Tt + i0 + r) * Tt + j0))[c] = z4;
    }
    return;
  }

  __shared__ float pbuf[4][32][36];  // stride 36: rows 16B-aligned, 2-way bank alias (free)
  const int w = tid >> 6, lane = tid & 63;
  const int b = w;  // wave == batch
  const int lrow = lane & 15, lk = lane >> 4;

  const size_t qbase = ((size_t)(b * Tt + i0 + lrow)) * C3 + h * 64 + lk * 8;
  const size_t kbase = ((size_t)(b * Tt + j0 + lrow)) * C3 + 1024 + h * 64 + lk * 8;
  bf16x8 q00 = *(const bf16x8*)(qkv + qbase);
  bf16x8 q01 = *(const bf16x8*)(qkv + qbase + 32);
  bf16x8 q10 = *(const bf16x8*)(qkv + qbase + (size_t)16 * C3);
  bf16x8 q11 = *(const bf16x8*)(qkv + qbase + (size_t)16 * C3 + 32);
  bf16x8 k00 = *(const bf16x8*)(qkv + kbase);
  bf16x8 k01 = *(const bf16x8*)(qkv + kbase + 32);
  bf16x8 k10 = *(const bf16x8*)(qkv + kbase + (size_t)16 * C3);
  bf16x8 k11 = *(const bf16x8*)(qkv + kbase + (size_t)16 * C3 + 32);

#pragma unroll
  for (int i2 = 0; i2 < 2; ++i2) {
    bf16x8 qa = i2 ? q10 : q00;
    bf16x8 qb = i2 ? q11 : q01;
#pragma unroll
    for (int j2 = 0; j2 < 2; ++j2) {
      f32x4 s = {0.f, 0.f, 0.f, 0.f};
      s = MFMA16(qa, j2 ? k10 : k00, s);
      s = MFMA16(qb, j2 ? k11 : k01, s);
      const int jg = j0 + j2 * 16 + lrow;
#pragma unroll
      for (int r = 0; r < 4; ++r) {
        int ig = i0 + i2 * 16 + lk * 4 + r;
        float2 st = stats[((size_t)(b * Hh + h)) * Tt + ig];
        float p = (jg <= ig) ? __expf(s[r] - st.x) * st.y : 0.f;
        pbuf[b][i2 * 16 + lk * 4 + r][j2 * 16 + lrow] = p;
      }
    }
  }
  __syncthreads();

  // att: 1024 float4s, wave-coherent batch, 128B-contiguous per row-octet
#pragma unroll
  for (int q = 0; q < 4; ++q) {
    int f = q * 256 + tid;
    int bq = f >> 8, row = (f >> 3) & 31, c4 = f & 7;
    float4 v = *(float4*)&pbuf[bq][row][c4 * 4];
    *(float4*)&att[(((size_t)(bq * Hh + h)) * Tt + i0 + row) * Tt + j0 + c4 * 4] = v;
  }
  // astd: each thread does 4 consecutive elements of one row
  {
    int row = tid >> 3, c4 = tid & 7;
    float4 p0 = *(float4*)&pbuf[0][row][c4 * 4];
    float4 p1 = *(float4*)&pbuf[1][row][c4 * 4];
    float4 p2 = *(float4*)&pbuf[2][row][c4 * 4];
    float4 p3 = *(float4*)&pbuf[3][row][c4 * 4];
    float4 o;
    {
      float s1, mean, var;
      s1 = p0.x + p1.x + p2.x + p3.x; mean = s1 * 0.25f;
      var = (p0.x*p0.x + p1.x*p1.x + p2.x*p2.x + p3.x*p3.x - 4.f*mean*mean) * (1.f/3.f);
      o.x = sqrtf(fmaxf(var, 0.f));
      s1 = p0.y + p1.y + p2.y + p3.y; mean = s1 * 0.25f;
      var = (p0.y*p0.y + p1.y*p1.y + p2.y*p2.y + p3.y*p3.y - 4.f*mean*mean) * (1.f/3.f);
      o.y = sqrtf(fmaxf(var, 0.f));
      s1 = p0.z + p1.z + p2.z + p3.z; mean = s1 * 0.25f;
      var = (p0.z*p0.z + p1.z*p1.z + p2.z*p2.z + p3.z*p3.z - 4.f*mean*mean) * (1.f/3.f);
      o.z = sqrtf(fmaxf(var, 0.f));
      s1 = p0.w + p1.w + p2.w + p3.w; mean = s1 * 0.25f;
      var = (p0.w*p0.w + p1.w*p1.w + p2.w*p2.w + p3.w*p3.w - 4.f*mean*mean) * (1.f/3.f);
      o.w = sqrtf(fmaxf(var, 0.f));
    }
    *(float4*)&astd[((size_t)h * Tt + i0 + row) * Tt + j0 + c4 * 4] = o;
  }
}

// ------------- banded (window=64) softmax @ V  ->  y_heads bf16 [B][T][C] -------------
// (round-1 verbatim, known-good)
__global__ __launch_bounds__(256) void k_bandy(const unsigned short* __restrict__ qkv,
                                               unsigned short* __restrict__ yh) {
  __shared__ unsigned short qls[64 * 66];
  __shared__ unsigned short kls[128 * 66];
  __shared__ unsigned short vls[128 * 66];
  __shared__ float pls[4][80];

  int blk = blockIdx.x;
  int it = blk & 15, h = (blk >> 4) & 15, b = blk >> 8;
  int i0 = it * 64;
  int jb = i0 - 64;
  int tid = threadIdx.x;

  // stage q rows [i0, i0+63], k/v rows [i0-64, i0+63] (row<0 -> zeros)
  for (int r = tid; r < 320; r += 256) {
    unsigned short* dst;
    int grow, sel;
    if (r < 64) { dst = qls + r * 66; grow = i0 + r; sel = 0; }
    else if (r < 192) { dst = kls + (r - 64) * 66; grow = jb + (r - 64); sel = 1; }
    else { dst = vls + (r - 192) * 66; grow = jb + (r - 192); sel = 2; }
    if (grow < 0) {
      for (int t = 0; t < 32; ++t) ((unsigned*)dst)[t] = 0u;
    } else {
      const unsigned* src = (const unsigned*)(qkv + ((size_t)(b * Tt + grow)) * C3 + sel * 1024 + h * 64);
      for (int t = 0; t < 32; ++t) ((unsigned*)dst)[t] = src[t];
    }
  }
  __syncthreads();

  const int w = tid >> 6, lane = tid & 63;
  for (int rr = 0; rr < 16; ++rr) {
    const int i = i0 + (w << 4) + rr;
    const int io = i - i0;
    const int ja = i - 64 + lane;           // key for this lane
    const unsigned* qrow = (const unsigned*)(qls + io * 66);
    const unsigned* krow = (const unsigned*)(kls + (size_t)(io + lane) * 66);
    const unsigned* kerow = (const unsigned*)(kls + (size_t)(io + 64) * 66);  // key j=i
    float sa = 0.f, se = 0.f;
#pragma unroll 8
    for (int t = 0; t < 32; ++t) {
      unsigned qq = qrow[t];
      float q0 = bf2f((unsigned short)qq), q1 = bf2f((unsigned short)(qq >> 16));
      unsigned kk = krow[t];
      sa = fmaf(q0, bf2f((unsigned short)kk), sa);
      sa = fmaf(q1, bf2f((unsigned short)(kk >> 16)), sa);
      unsigned ke = kerow[t];
      se = fmaf(q0, bf2f((unsigned short)ke), se);
      se = fmaf(q1, bf2f((unsigned short)(ke >> 16)), se);
    }
    if (ja < 0) sa = -1e30f;
    float m = sa;
    m = fmaxf(m, __shfl_xor(m, 1));
    m = fmaxf(m, __shfl_xor(m, 2));
    m = fmaxf(m, __shfl_xor(m, 4));
    m = fmaxf(m, __shfl_xor(m, 8));
    m = fmaxf(m, __shfl_xor(m, 16));
    m = fmaxf(m, __shfl_xor(m, 32));
    m = fmaxf(m, se);  // se identical on all lanes
    float pa = __expf(sa - m);
    float pe = __expf(se - m);
    float sum = pa;
    sum += __shfl_xor(sum, 1);
    sum += __shfl_xor(sum, 2);
    sum += __shfl_xor(sum, 4);
    sum += __shfl_xor(sum, 8);
    sum += __shfl_xor(sum, 16);
    sum += __shfl_xor(sum, 32);
    sum += pe;
    float rl = 1.0f / sum;
    pls[w][lane] = pa * rl;
    if (lane == 0) pls[w][64] = pe * rl;
    // PV: lane owns output dim d = lane; keys are idx = io + t, t=0..64
    float y = 0.f;
#pragma unroll 4
    for (int t = 0; t <= 64; ++t)
      y = fmaf(pls[w][t], bf2f(vls[(size_t)(io + t) * 66 + lane]), y);
    yh[((size_t)(b * Tt + i)) * 1024 + h * 64 + lane] = f2bf(y);
  }
}

// ============================ host ============================
extern "C" void kernel_launch(void* const* d_in, const int* in_sizes, int n_in,
                              void* d_out, int out_size, void* d_ws, size_t ws_size,
                              hipStream_t stream) {
  const float* x = (const float*)d_in[0];
  const float* Wa = (const float*)d_in[1];
  const float* Wp = (const float*)d_in[2];

  float* out = (float*)d_out;
  float* y_out = out;                               // [4,1024,1024]
  float* att = out + (size_t)4194304;               // [4,16,1024,1024]
  float* astd = out + (size_t)71303168;             // [16,1024,1024]

  // d_ws scratch: qkv bf16 | y_heads bf16 | WtP bf16 | stats   (36.2 MB)
  char* ws = (char*)d_ws;
  unsigned short* qkv = (unsigned short*)ws;                 // 25165824 B
  unsigned short* yh = (unsigned short*)(ws + 25165824);     // 8388608 B
  unsigned short* WtP = (unsigned short*)(ws + 33554432);    // 2097152 B
  float2* stats = (float2*)(ws + 35651584);                  // 524288 B

  // park WtA + x_bf16 inside the y output region (dead until final GEMM writes y)
  char* yreg = (char*)d_out;
  unsigned short* WtA = (unsigned short*)yreg;               // 6291456 B
  unsigned short* xbf = (unsigned short*)(yreg + 6291456);   // 8388608 B

  k_convert<<<4096, 256, 0, stream>>>(x, xbf, 1048576);
  k_transconv<<<dim3(96, 32), 256, 0, stream>>>(Wa, WtA, 1024, 3072);
  k_transconv<<<dim3(32, 32), 256, 0, stream>>>(Wp, WtP, 1024, 1024);
  // qkv = x @ W_attn  (q pre-scaled by 1/8), bf16 out
  k_gemm_bt<1, 1><<<dim3(32, 24), 256, 0, stream>>>(xbf, WtA, qkv, 4096, 3072, 1024);
  k_stats<<<1024, 256, 0, stream>>>(qkv, stats);
  k_att<<<dim3(32, 32, 16), 256, 0, stream>>>(qkv, stats, att, astd);
  k_bandy<<<1024, 256, 0, stream>>>(qkv, yh);
  // y = y_heads @ W_proj, fp32 out (overwrites the WtA/xbf scratch in-place)
  k_gemm_bt<0, 0><<<dim3(32, 8), 256, 0, stream>>>(yh, WtP, y_out, 4096, 1024, 1024);
}

// Round 4
// 337.014 us; speedup vs baseline: 1.3347x; 1.1887x over previous
//
#include <hip/hip_runtime.h>
#include <hip/hip_bf16.h>
#include <stdint.h>

// Problem constants
#define Bb 4
#define Tt 1024
#define Hh 16
#define HD 64
#define C3 3072
#define WIN 64  // MEMORY

typedef __bf16 bf16x8 __attribute__((ext_vector_type(8)));
typedef float f32x4 __attribute__((ext_vector_type(4)));

#define MFMA16(a, b, c) __builtin_amdgcn_mfma_f32_16x16x32_bf16((a), (b), (c), 0, 0, 0)

static __device__ __forceinline__ unsigned short f2bf(float f) {
  union { float f; unsigned u; } v; v.f = f;
  unsigned r = (v.u + 0x7FFFu + ((v.u >> 16) & 1u)) >> 16;
  return (unsigned short)r;
}
static __device__ __forceinline__ float bf2f(unsigned short h) {
  union { unsigned u; float f; } v; v.u = ((unsigned)h) << 16;
  return v.f;
}

// ---------------- fp32 -> bf16 convert (vectorized) ----------------
__global__ __launch_bounds__(256) void k_convert(const float* __restrict__ in,
                                                 unsigned short* __restrict__ out, int n4) {
  int i = blockIdx.x * 256 + threadIdx.x;
  if (i >= n4) return;
  float4 v = ((const float4*)in)[i];
  ushort4 o;
  o.x = f2bf(v.x); o.y = f2bf(v.y); o.z = f2bf(v.z); o.w = f2bf(v.w);
  ((ushort4*)out)[i] = o;
}

// ------------- transpose + convert: W [K][N] fp32 -> Wt [N][K] bf16 -------------
__global__ __launch_bounds__(256) void k_transconv(const float* __restrict__ Win,
                                                   unsigned short* __restrict__ Wt,
                                                   int K, int N) {
  __shared__ float tile[32][33];
  int n0 = blockIdx.x * 32, k0 = blockIdx.y * 32;
  int tx = threadIdx.x & 31, ty = threadIdx.x >> 5;
  for (int r = ty; r < 32; r += 8)
    tile[r][tx] = Win[(size_t)(k0 + r) * N + n0 + tx];
  __syncthreads();
  for (int r = ty; r < 32; r += 8)
    Wt[(size_t)(n0 + r) * K + k0 + tx] = f2bf(tile[tx][r]);
}

// ------------- bf16 GEMM: C[M][N] = A[M][K] * Bt[N][K]^T  (m97-style 128x128 tile) -------------
template <int BF16_OUT, int SCALEQ>
__global__ __launch_bounds__(256) void k_gemm_bt(const unsigned short* __restrict__ A,
                                                 const unsigned short* __restrict__ Bt,
                                                 void* __restrict__ Cv, int M, int N, int K) {
  __shared__ unsigned short lds[2 * 128 * 32];
  unsigned short* as_ = lds;
  unsigned short* bs_ = lds + 128 * 32;
  const int tid = threadIdx.x;
  const int m0 = blockIdx.x * 128, n0 = blockIdx.y * 128;
  const int w = tid >> 6, lane = tid & 63;
  const int wm = (w >> 1) * 64, wn = (w & 1) * 64;
  const int lrow = lane & 15, lk = lane >> 4;

  f32x4 z = {0.f, 0.f, 0.f, 0.f};
  f32x4 acc[4][4];
#pragma unroll
  for (int i = 0; i < 4; ++i)
#pragma unroll
    for (int j = 0; j < 4; ++j) acc[i][j] = z;

  const int nk = K >> 5;
  for (int kt = 0; kt < nk; ++kt) {
    const int k0 = kt << 5;
    __syncthreads();
#pragma unroll
    for (int p = 0; p < 2; ++p) {
      int seg = tid + p * 256;
      int row = seg >> 2, ks = (seg & 3) << 3;
      __builtin_amdgcn_global_load_lds(
          (__attribute__((address_space(1))) void*)(A + (size_t)(m0 + row) * K + k0 + ks),
          (__attribute__((address_space(3))) void*)(as_ + seg * 8), 16, 0, 0);
      __builtin_amdgcn_global_load_lds(
          (__attribute__((address_space(1))) void*)(Bt + (size_t)(n0 + row) * K + k0 + ks),
          (__attribute__((address_space(3))) void*)(bs_ + seg * 8), 16, 0, 0);
    }
    __syncthreads();
    bf16x8 af[4], bfr[4];
#pragma unroll
    for (int f = 0; f < 4; ++f) {
      af[f] = *(const bf16x8*)(as_ + (wm + f * 16 + lrow) * 32 + lk * 8);
      bfr[f] = *(const bf16x8*)(bs_ + (wn + f * 16 + lrow) * 32 + lk * 8);
    }
#pragma unroll
    for (int i = 0; i < 4; ++i)
#pragma unroll
      for (int j = 0; j < 4; ++j) acc[i][j] = MFMA16(af[i], bfr[j], acc[i][j]);
  }
  // epilogue: D row = (lane>>4)*4+r, col = lane&15
  const int r0 = lk * 4;
#pragma unroll
  for (int i = 0; i < 4; ++i)
#pragma unroll
    for (int j = 0; j < 4; ++j)
#pragma unroll
      for (int r = 0; r < 4; ++r) {
        int gm = m0 + wm + i * 16 + r0 + r;
        int gn = n0 + wn + j * 16 + lrow;
        float v = acc[i][j][r];
        if (SCALEQ) {
          if (gn < 1024) v *= 0.125f;  // fold 1/sqrt(hd) into q
        }
        if (BF16_OUT)
          ((unsigned short*)Cv)[(size_t)gm * N + gn] = f2bf(v);
        else
          ((float*)Cv)[(size_t)gm * N + gn] = v;
      }
}

// ------------- causal softmax row stats: m and 1/l per (b,h,i) -------------
// Per-lane online softmax (NO cross-lane ops in the j loop); merge once at end.
__global__ __launch_bounds__(256) void k_stats(const unsigned short* __restrict__ qkv,
                                               float2* __restrict__ stats) {
  int blk = blockIdx.x;
  int it = blk & 15, h = (blk >> 4) & 15, b = blk >> 8;
  int w = threadIdx.x >> 6, lane = threadIdx.x & 63;
  int lrow = lane & 15, lk = lane >> 4;
  int ibase = it * 64 + w * 16;

  const size_t qrow = ((size_t)(b * Tt + ibase + lrow)) * C3 + h * 64 + lk * 8;
  bf16x8 qf0 = *(const bf16x8*)(qkv + qrow);
  bf16x8 qf1 = *(const bf16x8*)(qkv + qrow + 32);

  float m[4] = {-1e30f, -1e30f, -1e30f, -1e30f};
  float l[4] = {0.f, 0.f, 0.f, 0.f};
  const int nt = (ibase + 15) >> 5;  // 32-wide j tiles, 0..nt inclusive
  for (int jt = 0; jt <= nt; ++jt) {
    const int j0 = jt * 32;
    const size_t krowa = ((size_t)(b * Tt + j0 + lrow)) * C3 + 1024 + h * 64 + lk * 8;
    const size_t krowb = krowa + (size_t)16 * C3;
    bf16x8 ka0 = *(const bf16x8*)(qkv + krowa);
    bf16x8 ka1 = *(const bf16x8*)(qkv + krowa + 32);
    bf16x8 kb0 = *(const bf16x8*)(qkv + krowb);
    bf16x8 kb1 = *(const bf16x8*)(qkv + krowb + 32);
    f32x4 sa = {0.f, 0.f, 0.f, 0.f}, sb = {0.f, 0.f, 0.f, 0.f};
    sa = MFMA16(qf0, ka0, sa);
    sa = MFMA16(qf1, ka1, sa);
    sb = MFMA16(qf0, kb0, sb);
    sb = MFMA16(qf1, kb1, sb);
    const int ja = j0 + lrow, jb2 = j0 + 16 + lrow;
#pragma unroll
    for (int r = 0; r < 4; ++r) {
      int ig = ibase + lk * 4 + r;
      int oka = (ja <= ig), okb = (jb2 <= ig);
      float va = oka ? sa[r] : -1e30f;
      float vb = okb ? sb[r] : -1e30f;
      float mn = fmaxf(m[r], fmaxf(va, vb));
      float pa = oka ? __expf(sa[r] - mn) : 0.f;   // explicit 0: exp(-1e30-(-1e30))=1 trap
      float pb = okb ? __expf(sb[r] - mn) : 0.f;
      l[r] = l[r] * __expf(m[r] - mn) + pa + pb;
      m[r] = mn;
    }
  }
  // merge (m,l) across the 16 lanes of each lrow group
#pragma unroll
  for (int r = 0; r < 4; ++r) {
    float mm = m[r], ll = l[r];
#pragma unroll
    for (int d = 1; d <= 8; d <<= 1) {
      float mo = __shfl_xor(mm, d);
      float lo = __shfl_xor(ll, d);
      float mn = fmaxf(mm, mo);
      ll = ll * __expf(mm - mn) + lo * __expf(mo - mn);
      mm = mn;
    }
    if (lrow == 0) {
      int ig = ibase + lk * 4 + r;
      stats[((size_t)(b * Hh + h)) * Tt + ig] = make_float2(mm, 1.0f / ll);
    }
  }
}

// ------------- att (full causal probs) + att_std, per 32x32 tile -------------
// wave = batch; probabilities staged in LDS; float4 stores for att and astd.
__global__ __launch_bounds__(256) void k_att(const unsigned short* __restrict__ qkv,
                                             const float2* __restrict__ stats,
                                             float* __restrict__ att, float* __restrict__ astd) {
  const int tj = blockIdx.x, ti = blockIdx.y, h = blockIdx.z;
  const int i0 = ti * 32, j0 = tj * 32;
  const int tid = threadIdx.x;

  if (tj > ti) {  // fully masked tile: stream zeros
    float4 z4 = make_float4(0.f, 0.f, 0.f, 0.f);
    for (int s = tid; s < 1024; s += 256) {
      int b = s >> 8, r = (s >> 3) & 31, c = s & 7;
      ((float4*)(att + (((size_t)(b * Hh + h)) * Tt + i0 + r) * Tt + j0))[c] = z4;
    }
    {
      int r = tid >> 3, c = tid & 7;
      ((float4*)(astd + ((size_t)h * Tt + i0 + r) * Tt + j0))[c] = z4;
    }
    return;
  }

  __shared__ float pbuf[4][32][36];  // stride 36: rows 16B-aligned, 2-way bank alias (free)
  const int w = tid >> 6, lane = tid & 63;
  const int b = w;  // wave == batch
  const int lrow = lane & 15, lk = lane >> 4;

  const size_t qbase = ((size_t)(b * Tt + i0 + lrow)) * C3 + h * 64 + lk * 8;
  const size_t kbase = ((size_t)(b * Tt + j0 + lrow)) * C3 + 1024 + h * 64 + lk * 8;
  bf16x8 q00 = *(const bf16x8*)(qkv + qbase);
  bf16x8 q01 = *(const bf16x8*)(qkv + qbase + 32);
  bf16x8 q10 = *(const bf16x8*)(qkv + qbase + (size_t)16 * C3);
  bf16x8 q11 = *(const bf16x8*)(qkv + qbase + (size_t)16 * C3 + 32);
  bf16x8 k00 = *(const bf16x8*)(qkv + kbase);
  bf16x8 k01 = *(const bf16x8*)(qkv + kbase + 32);
  bf16x8 k10 = *(const bf16x8*)(qkv + kbase + (size_t)16 * C3);
  bf16x8 k11 = *(const bf16x8*)(qkv + kbase + (size_t)16 * C3 + 32);

#pragma unroll
  for (int i2 = 0; i2 < 2; ++i2) {
    bf16x8 qa = i2 ? q10 : q00;
    bf16x8 qb = i2 ? q11 : q01;
    // hoisted row stats for this i2 (4 rows per lane)
    float2 st[4];
#pragma unroll
    for (int r = 0; r < 4; ++r)
      st[r] = stats[((size_t)(b * Hh + h)) * Tt + i0 + i2 * 16 + lk * 4 + r];
#pragma unroll
    for (int j2 = 0; j2 < 2; ++j2) {
      f32x4 s = {0.f, 0.f, 0.f, 0.f};
      s = MFMA16(qa, j2 ? k10 : k00, s);
      s = MFMA16(qb, j2 ? k11 : k01, s);
      const int jg = j0 + j2 * 16 + lrow;
#pragma unroll
      for (int r = 0; r < 4; ++r) {
        int ig = i0 + i2 * 16 + lk * 4 + r;
        float p = (jg <= ig) ? __expf(s[r] - st[r].x) * st[r].y : 0.f;
        pbuf[b][i2 * 16 + lk * 4 + r][j2 * 16 + lrow] = p;
      }
    }
  }
  __syncthreads();

  // att: 1024 float4s, wave-coherent batch, 128B-contiguous per row-octet
#pragma unroll
  for (int q = 0; q < 4; ++q) {
    int f = q * 256 + tid;
    int bq = f >> 8, row = (f >> 3) & 31, c4 = f & 7;
    float4 v = *(float4*)&pbuf[bq][row][c4 * 4];
    *(float4*)&att[(((size_t)(bq * Hh + h)) * Tt + i0 + row) * Tt + j0 + c4 * 4] = v;
  }
  // astd: each thread does 4 consecutive elements of one row
  {
    int row = tid >> 3, c4 = tid & 7;
    float4 p0 = *(float4*)&pbuf[0][row][c4 * 4];
    float4 p1 = *(float4*)&pbuf[1][row][c4 * 4];
    float4 p2 = *(float4*)&pbuf[2][row][c4 * 4];
    float4 p3 = *(float4*)&pbuf[3][row][c4 * 4];
    float4 o;
    {
      float s1, mean, var;
      s1 = p0.x + p1.x + p2.x + p3.x; mean = s1 * 0.25f;
      var = (p0.x*p0.x + p1.x*p1.x + p2.x*p2.x + p3.x*p3.x - 4.f*mean*mean) * (1.f/3.f);
      o.x = sqrtf(fmaxf(var, 0.f));
      s1 = p0.y + p1.y + p2.y + p3.y; mean = s1 * 0.25f;
      var = (p0.y*p0.y + p1.y*p1.y + p2.y*p2.y + p3.y*p3.y - 4.f*mean*mean) * (1.f/3.f);
      o.y = sqrtf(fmaxf(var, 0.f));
      s1 = p0.z + p1.z + p2.z + p3.z; mean = s1 * 0.25f;
      var = (p0.z*p0.z + p1.z*p1.z + p2.z*p2.z + p3.z*p3.z - 4.f*mean*mean) * (1.f/3.f);
      o.z = sqrtf(fmaxf(var, 0.f));
      s1 = p0.w + p1.w + p2.w + p3.w; mean = s1 * 0.25f;
      var = (p0.w*p0.w + p1.w*p1.w + p2.w*p2.w + p3.w*p3.w - 4.f*mean*mean) * (1.f/3.f);
      o.w = sqrtf(fmaxf(var, 0.f));
    }
    *(float4*)&astd[((size_t)h * Tt + i0 + row) * Tt + j0 + c4 * 4] = o;
  }
}

// ------------- banded (window=64) softmax @ V  ->  y_heads bf16 [B][T][C] -------------
// (round-1 verbatim, known-good)
__global__ __launch_bounds__(256) void k_bandy(const unsigned short* __restrict__ qkv,
                                               unsigned short* __restrict__ yh) {
  __shared__ unsigned short qls[64 * 66];
  __shared__ unsigned short kls[128 * 66];
  __shared__ unsigned short vls[128 * 66];
  __shared__ float pls[4][80];

  int blk = blockIdx.x;
  int it = blk & 15, h = (blk >> 4) & 15, b = blk >> 8;
  int i0 = it * 64;
  int jb = i0 - 64;
  int tid = threadIdx.x;

  // stage q rows [i0, i0+63], k/v rows [i0-64, i0+63] (row<0 -> zeros)
  for (int r = tid; r < 320; r += 256) {
    unsigned short* dst;
    int grow, sel;
    if (r < 64) { dst = qls + r * 66; grow = i0 + r; sel = 0; }
    else if (r < 192) { dst = kls + (r - 64) * 66; grow = jb + (r - 64); sel = 1; }
    else { dst = vls + (r - 192) * 66; grow = jb + (r - 192); sel = 2; }
    if (grow < 0) {
      for (int t = 0; t < 32; ++t) ((unsigned*)dst)[t] = 0u;
    } else {
      const unsigned* src = (const unsigned*)(qkv + ((size_t)(b * Tt + grow)) * C3 + sel * 1024 + h * 64);
      for (int t = 0; t < 32; ++t) ((unsigned*)dst)[t] = src[t];
    }
  }
  __syncthreads();

  const int w = tid >> 6, lane = tid & 63;
  for (int rr = 0; rr < 16; ++rr) {
    const int i = i0 + (w << 4) + rr;
    const int io = i - i0;
    const int ja = i - 64 + lane;           // key for this lane
    const unsigned* qrow = (const unsigned*)(qls + io * 66);
    const unsigned* krow = (const unsigned*)(kls + (size_t)(io + lane) * 66);
    const unsigned* kerow = (const unsigned*)(kls + (size_t)(io + 64) * 66);  // key j=i
    float sa = 0.f, se = 0.f;
#pragma unroll 8
    for (int t = 0; t < 32; ++t) {
      unsigned qq = qrow[t];
      float q0 = bf2f((unsigned short)qq), q1 = bf2f((unsigned short)(qq >> 16));
      unsigned kk = krow[t];
      sa = fmaf(q0, bf2f((unsigned short)kk), sa);
      sa = fmaf(q1, bf2f((unsigned short)(kk >> 16)), sa);
      unsigned ke = kerow[t];
      se = fmaf(q0, bf2f((unsigned short)ke), se);
      se = fmaf(q1, bf2f((unsigned short)(ke >> 16)), se);
    }
    if (ja < 0) sa = -1e30f;
    float m = sa;
    m = fmaxf(m, __shfl_xor(m, 1));
    m = fmaxf(m, __shfl_xor(m, 2));
    m = fmaxf(m, __shfl_xor(m, 4));
    m = fmaxf(m, __shfl_xor(m, 8));
    m = fmaxf(m, __shfl_xor(m, 16));
    m = fmaxf(m, __shfl_xor(m, 32));
    m = fmaxf(m, se);  // se identical on all lanes
    float pa = __expf(sa - m);
    float pe = __expf(se - m);
    float sum = pa;
    sum += __shfl_xor(sum, 1);
    sum += __shfl_xor(sum, 2);
    sum += __shfl_xor(sum, 4);
    sum += __shfl_xor(sum, 8);
    sum += __shfl_xor(sum, 16);
    sum += __shfl_xor(sum, 32);
    sum += pe;
    float rl = 1.0f / sum;
    pls[w][lane] = pa * rl;
    if (lane == 0) pls[w][64] = pe * rl;
    // PV: lane owns output dim d = lane; keys are idx = io + t, t=0..64
    float y = 0.f;
#pragma unroll 4
    for (int t = 0; t <= 64; ++t)
      y = fmaf(pls[w][t], bf2f(vls[(size_t)(io + t) * 66 + lane]), y);
    yh[((size_t)(b * Tt + i)) * 1024 + h * 64 + lane] = f2bf(y);
  }
}

// ============================ host ============================
extern "C" void kernel_launch(void* const* d_in, const int* in_sizes, int n_in,
                              void* d_out, int out_size, void* d_ws, size_t ws_size,
                              hipStream_t stream) {
  const float* x = (const float*)d_in[0];
  const float* Wa = (const float*)d_in[1];
  const float* Wp = (const float*)d_in[2];

  float* out = (float*)d_out;
  float* y_out = out;                               // [4,1024,1024]
  float* att = out + (size_t)4194304;               // [4,16,1024,1024]
  float* astd = out + (size_t)71303168;             // [16,1024,1024]

  // d_ws scratch: qkv bf16 | y_heads bf16 | WtP bf16 | stats   (36.2 MB)
  char* ws = (char*)d_ws;
  unsigned short* qkv = (unsigned short*)ws;                 // 25165824 B
  unsigned short* yh = (unsigned short*)(ws + 25165824);     // 8388608 B
  unsigned short* WtP = (unsigned short*)(ws + 33554432);    // 2097152 B
  float2* stats = (float2*)(ws + 35651584);                  // 524288 B

  // park WtA + x_bf16 inside the y output region (dead until final GEMM writes y)
  char* yreg = (char*)d_out;
  unsigned short* WtA = (unsigned short*)yreg;               // 6291456 B
  unsigned short* xbf = (unsigned short*)(yreg + 6291456);   // 8388608 B

  k_convert<<<4096, 256, 0, stream>>>(x, xbf, 1048576);
  k_transconv<<<dim3(96, 32), 256, 0, stream>>>(Wa, WtA, 1024, 3072);
  k_transconv<<<dim3(32, 32), 256, 0, stream>>>(Wp, WtP, 1024, 1024);
  // qkv = x @ W_attn  (q pre-scaled by 1/8), bf16 out
  k_gemm_bt<1, 1><<<dim3(32, 24), 256, 0, stream>>>(xbf, WtA, qkv, 4096, 3072, 1024);
  k_stats<<<1024, 256, 0, stream>>>(qkv, stats);
  k_att<<<dim3(32, 32, 16), 256, 0, stream>>>(qkv, stats, att, astd);
  k_bandy<<<1024, 256, 0, stream>>>(qkv, yh);
  // y = y_heads @ W_proj, fp32 out (overwrites the WtA/xbf scratch in-place)
  k_gemm_bt<0, 0><<<dim3(32, 8), 256, 0, stream>>>(yh, WtP, y_out, 4096, 1024, 1024);
}

// Round 5
// 309.556 us; speedup vs baseline: 1.4531x; 1.0887x over previous
//
#include <hip/hip_runtime.h>
#include <hip/hip_bf16.h>
#include <stdint.h>

// Problem constants
#define Bb 4
#define Tt 1024
#define Hh 16
#define HD 64
#define C3 3072
#define WIN 64  // MEMORY

typedef __bf16 bf16x8 __attribute__((ext_vector_type(8)));
typedef float f32x4 __attribute__((ext_vector_type(4)));

#define MFMA16(a, b, c) __builtin_amdgcn_mfma_f32_16x16x32_bf16((a), (b), (c), 0, 0, 0)

static __device__ __forceinline__ unsigned short f2bf(float f) {
  union { float f; unsigned u; } v; v.f = f;
  unsigned r = (v.u + 0x7FFFu + ((v.u >> 16) & 1u)) >> 16;
  return (unsigned short)r;
}
static __device__ __forceinline__ float bf2f(unsigned short h) {
  union { unsigned u; float f; } v; v.u = ((unsigned)h) << 16;
  return v.f;
}

// ---------------- fp32 -> bf16 convert (vectorized) ----------------
__global__ __launch_bounds__(256) void k_convert(const float* __restrict__ in,
                                                 unsigned short* __restrict__ out, int n4) {
  int i = blockIdx.x * 256 + threadIdx.x;
  if (i >= n4) return;
  float4 v = ((const float4*)in)[i];
  ushort4 o;
  o.x = f2bf(v.x); o.y = f2bf(v.y); o.z = f2bf(v.z); o.w = f2bf(v.w);
  ((ushort4*)out)[i] = o;
}

// ------------- transpose + convert: W [K][N] fp32 -> Wt [N][K] bf16 -------------
__global__ __launch_bounds__(256) void k_transconv(const float* __restrict__ Win,
                                                   unsigned short* __restrict__ Wt,
                                                   int K, int N) {
  __shared__ float tile[32][33];
  int n0 = blockIdx.x * 32, k0 = blockIdx.y * 32;
  int tx = threadIdx.x & 31, ty = threadIdx.x >> 5;
  for (int r = ty; r < 32; r += 8)
    tile[r][tx] = Win[(size_t)(k0 + r) * N + n0 + tx];
  __syncthreads();
  for (int r = ty; r < 32; r += 8)
    Wt[(size_t)(n0 + r) * K + k0 + tx] = f2bf(tile[tx][r]);
}

// ------------- bf16 GEMM: C[M][N] = A[M][K] * Bt[N][K]^T  (m97-style 128x128 tile) -------------
template <int BF16_OUT, int SCALEQ>
__global__ __launch_bounds__(256) void k_gemm_bt(const unsigned short* __restrict__ A,
                                                 const unsigned short* __restrict__ Bt,
                                                 void* __restrict__ Cv, int M, int N, int K) {
  __shared__ unsigned short lds[2 * 128 * 32];
  unsigned short* as_ = lds;
  unsigned short* bs_ = lds + 128 * 32;
  const int tid = threadIdx.x;
  const int m0 = blockIdx.x * 128, n0 = blockIdx.y * 128;
  const int w = tid >> 6, lane = tid & 63;
  const int wm = (w >> 1) * 64, wn = (w & 1) * 64;
  const int lrow = lane & 15, lk = lane >> 4;

  f32x4 z = {0.f, 0.f, 0.f, 0.f};
  f32x4 acc[4][4];
#pragma unroll
  for (int i = 0; i < 4; ++i)
#pragma unroll
    for (int j = 0; j < 4; ++j) acc[i][j] = z;

  const int nk = K >> 5;
  for (int kt = 0; kt < nk; ++kt) {
    const int k0 = kt << 5;
    __syncthreads();
#pragma unroll
    for (int p = 0; p < 2; ++p) {
      int seg = tid + p * 256;
      int row = seg >> 2, ks = (seg & 3) << 3;
      __builtin_amdgcn_global_load_lds(
          (__attribute__((address_space(1))) void*)(A + (size_t)(m0 + row) * K + k0 + ks),
          (__attribute__((address_space(3))) void*)(as_ + seg * 8), 16, 0, 0);
      __builtin_amdgcn_global_load_lds(
          (__attribute__((address_space(1))) void*)(Bt + (size_t)(n0 + row) * K + k0 + ks),
          (__attribute__((address_space(3))) void*)(bs_ + seg * 8), 16, 0, 0);
    }
    __syncthreads();
    bf16x8 af[4], bfr[4];
#pragma unroll
    for (int f = 0; f < 4; ++f) {
      af[f] = *(const bf16x8*)(as_ + (wm + f * 16 + lrow) * 32 + lk * 8);
      bfr[f] = *(const bf16x8*)(bs_ + (wn + f * 16 + lrow) * 32 + lk * 8);
    }
#pragma unroll
    for (int i = 0; i < 4; ++i)
#pragma unroll
      for (int j = 0; j < 4; ++j) acc[i][j] = MFMA16(af[i], bfr[j], acc[i][j]);
  }
  // epilogue: D row = (lane>>4)*4+r, col = lane&15
  const int r0 = lk * 4;
#pragma unroll
  for (int i = 0; i < 4; ++i)
#pragma unroll
    for (int j = 0; j < 4; ++j)
#pragma unroll
      for (int r = 0; r < 4; ++r) {
        int gm = m0 + wm + i * 16 + r0 + r;
        int gn = n0 + wn + j * 16 + lrow;
        float v = acc[i][j][r];
        if (SCALEQ) {
          if (gn < 1024) v *= 0.125f;  // fold 1/sqrt(hd) into q
        }
        if (BF16_OUT)
          ((unsigned short*)Cv)[(size_t)gm * N + gn] = f2bf(v);
        else
          ((float*)Cv)[(size_t)gm * N + gn] = v;
      }
}

// ------------- fused att: stats (pass1) + probs/std (pass2), 32 rows x all cols per block ----
// grid (ti=32, h=16); wave = batch. Per wave: rows [i0, i0+32) as two 16-row MFMA subtiles.
__global__ __launch_bounds__(256) void k_att(const unsigned short* __restrict__ qkv,
                                             float* __restrict__ att, float* __restrict__ astd) {
  const int ti = blockIdx.x, h = blockIdx.y;
  const int i0 = ti * 32;
  const int tid = threadIdx.x;
  const int w = tid >> 6, lane = tid & 63;
  const int b = w;  // wave == batch
  const int lrow = lane & 15, lk = lane >> 4;

  __shared__ float pbuf[4][32][36];  // [batch][row][col], stride 36 (16B-aligned rows)

  // q fragments: rows i0 + i2*16 + lrow, dims split in two 32-chunks (pre-scaled by 1/8 in GEMM)
  const size_t qbase = ((size_t)(b * Tt + i0 + lrow)) * C3 + h * 64 + lk * 8;
  bf16x8 q00 = *(const bf16x8*)(qkv + qbase);
  bf16x8 q01 = *(const bf16x8*)(qkv + qbase + 32);
  bf16x8 q10 = *(const bf16x8*)(qkv + qbase + (size_t)16 * C3);
  bf16x8 q11 = *(const bf16x8*)(qkv + qbase + (size_t)16 * C3 + 32);

  // ---- pass 1: per-lane online (m,l) over j-tiles 0..ti (verified round-4 k_stats math) ----
  float m[2][4], l[2][4];
#pragma unroll
  for (int i2 = 0; i2 < 2; ++i2)
#pragma unroll
    for (int r = 0; r < 4; ++r) { m[i2][r] = -1e30f; l[i2][r] = 0.f; }

  for (int jt = 0; jt <= ti; ++jt) {
    const int j0 = jt * 32;
    const size_t krowa = ((size_t)(b * Tt + j0 + lrow)) * C3 + 1024 + h * 64 + lk * 8;
    const size_t krowb = krowa + (size_t)16 * C3;
    bf16x8 k00 = *(const bf16x8*)(qkv + krowa);
    bf16x8 k01 = *(const bf16x8*)(qkv + krowa + 32);
    bf16x8 k10 = *(const bf16x8*)(qkv + krowb);
    bf16x8 k11 = *(const bf16x8*)(qkv + krowb + 32);
    const int ja = j0 + lrow, jb2 = j0 + 16 + lrow;
#pragma unroll
    for (int i2 = 0; i2 < 2; ++i2) {
      bf16x8 qa = i2 ? q10 : q00;
      bf16x8 qb = i2 ? q11 : q01;
      f32x4 sa = {0.f, 0.f, 0.f, 0.f}, sb = {0.f, 0.f, 0.f, 0.f};
      sa = MFMA16(qa, k00, sa);
      sa = MFMA16(qb, k01, sa);
      sb = MFMA16(qa, k10, sb);
      sb = MFMA16(qb, k11, sb);
#pragma unroll
      for (int r = 0; r < 4; ++r) {
        int ig = i0 + i2 * 16 + lk * 4 + r;
        int oka = (ja <= ig), okb = (jb2 <= ig);
        float va = oka ? sa[r] : -1e30f;
        float vb = okb ? sb[r] : -1e30f;
        float mn = fmaxf(m[i2][r], fmaxf(va, vb));
        float pa = oka ? __expf(sa[r] - mn) : 0.f;  // explicit 0 (exp(-inf - -inf) trap)
        float pb = okb ? __expf(sb[r] - mn) : 0.f;
        l[i2][r] = l[i2][r] * __expf(m[i2][r] - mn) + pa + pb;
        m[i2][r] = mn;
      }
    }
  }
  // butterfly merge across the 16-lane lrow groups; all lanes get the result
  float rl[2][4];
#pragma unroll
  for (int i2 = 0; i2 < 2; ++i2)
#pragma unroll
    for (int r = 0; r < 4; ++r) {
      float mm = m[i2][r], ll = l[i2][r];
#pragma unroll
      for (int d = 1; d <= 8; d <<= 1) {
        float mo = __shfl_xor(mm, d);
        float lo = __shfl_xor(ll, d);
        float mn = fmaxf(mm, mo);
        ll = ll * __expf(mm - mn) + lo * __expf(mo - mn);
        mm = mn;
      }
      m[i2][r] = mm;
      rl[i2][r] = 1.0f / ll;
    }

  // ---- pass 2: sweep all 32 j-tiles; probs + att stores + astd ----
  const float4 z4 = make_float4(0.f, 0.f, 0.f, 0.f);
  for (int jt = 0; jt < 32; ++jt) {
    const int j0 = jt * 32;
    if (jt > ti) {  // fully masked: stream zeros, no LDS, no barriers
      // att zeros: wave w covers its batch, 4 float4 per lane
#pragma unroll
      for (int q = 0; q < 4; ++q) {
        int f = q * 64 + lane;
        int row = f >> 3, c4 = f & 7;
        *(float4*)&att[(((size_t)(b * Hh + h)) * Tt + i0 + row) * Tt + j0 + c4 * 4] = z4;
      }
      {  // astd zeros: 256 threads, one float4 each
        int row = tid >> 3, c4 = tid & 7;
        *(float4*)&astd[((size_t)h * Tt + i0 + row) * Tt + j0 + c4 * 4] = z4;
      }
      continue;
    }
    // recompute scores for this tile
    const size_t krowa = ((size_t)(b * Tt + j0 + lrow)) * C3 + 1024 + h * 64 + lk * 8;
    const size_t krowb = krowa + (size_t)16 * C3;
    bf16x8 k00 = *(const bf16x8*)(qkv + krowa);
    bf16x8 k01 = *(const bf16x8*)(qkv + krowa + 32);
    bf16x8 k10 = *(const bf16x8*)(qkv + krowb);
    bf16x8 k11 = *(const bf16x8*)(qkv + krowb + 32);
#pragma unroll
    for (int i2 = 0; i2 < 2; ++i2) {
      bf16x8 qa = i2 ? q10 : q00;
      bf16x8 qb = i2 ? q11 : q01;
#pragma unroll
      for (int j2 = 0; j2 < 2; ++j2) {
        f32x4 s = {0.f, 0.f, 0.f, 0.f};
        s = MFMA16(qa, j2 ? k10 : k00, s);
        s = MFMA16(qb, j2 ? k11 : k01, s);
        const int jg = j0 + j2 * 16 + lrow;
#pragma unroll
        for (int r = 0; r < 4; ++r) {
          int ig = i0 + i2 * 16 + lk * 4 + r;
          float p = (jg <= ig) ? __expf(s[r] - m[i2][r]) * rl[i2][r] : 0.f;
          pbuf[b][i2 * 16 + lk * 4 + r][j2 * 16 + lrow] = p;
        }
      }
    }
    // att stores: wave reads only ITS OWN pbuf[b] (same-wave LDS, no barrier needed)
#pragma unroll
    for (int q = 0; q < 4; ++q) {
      int f = q * 64 + lane;
      int row = f >> 3, c4 = f & 7;
      float4 v = *(float4*)&pbuf[b][row][c4 * 4];
      *(float4*)&att[(((size_t)(b * Hh + h)) * Tt + i0 + row) * Tt + j0 + c4 * 4] = v;
    }
    __syncthreads();  // all batches' pbuf visible
    {  // astd over batch dim
      int row = tid >> 3, c4 = tid & 7;
      float4 p0 = *(float4*)&pbuf[0][row][c4 * 4];
      float4 p1 = *(float4*)&pbuf[1][row][c4 * 4];
      float4 p2 = *(float4*)&pbuf[2][row][c4 * 4];
      float4 p3 = *(float4*)&pbuf[3][row][c4 * 4];
      float4 o;
      float s1, mean, var;
      s1 = p0.x + p1.x + p2.x + p3.x; mean = s1 * 0.25f;
      var = (p0.x*p0.x + p1.x*p1.x + p2.x*p2.x + p3.x*p3.x - 4.f*mean*mean) * (1.f/3.f);
      o.x = sqrtf(fmaxf(var, 0.f));
      s1 = p0.y + p1.y + p2.y + p3.y; mean = s1 * 0.25f;
      var = (p0.y*p0.y + p1.y*p1.y + p2.y*p2.y + p3.y*p3.y - 4.f*mean*mean) * (1.f/3.f);
      o.y = sqrtf(fmaxf(var, 0.f));
      s1 = p0.z + p1.z + p2.z + p3.z; mean = s1 * 0.25f;
      var = (p0.z*p0.z + p1.z*p1.z + p2.z*p2.z + p3.z*p3.z - 4.f*mean*mean) * (1.f/3.f);
      o.z = sqrtf(fmaxf(var, 0.f));
      s1 = p0.w + p1.w + p2.w + p3.w; mean = s1 * 0.25f;
      var = (p0.w*p0.w + p1.w*p1.w + p2.w*p2.w + p3.w*p3.w - 4.f*mean*mean) * (1.f/3.f);
      o.w = sqrtf(fmaxf(var, 0.f));
      *(float4*)&astd[((size_t)h * Tt + i0 + row) * Tt + j0 + c4 * 4] = o;
    }
    __syncthreads();  // protect pbuf reuse in next jt
  }
}

// ------------- banded (window=64) softmax @ V  ->  y_heads bf16 [B][T][C] -------------
// (round-1 verbatim, known-good)
__global__ __launch_bounds__(256) void k_bandy(const unsigned short* __restrict__ qkv,
                                               unsigned short* __restrict__ yh) {
  __shared__ unsigned short qls[64 * 66];
  __shared__ unsigned short kls[128 * 66];
  __shared__ unsigned short vls[128 * 66];
  __shared__ float pls[4][80];

  int blk = blockIdx.x;
  int it = blk & 15, h = (blk >> 4) & 15, b = blk >> 8;
  int i0 = it * 64;
  int jb = i0 - 64;
  int tid = threadIdx.x;

  // stage q rows [i0, i0+63], k/v rows [i0-64, i0+63] (row<0 -> zeros)
  for (int r = tid; r < 320; r += 256) {
    unsigned short* dst;
    int grow, sel;
    if (r < 64) { dst = qls + r * 66; grow = i0 + r; sel = 0; }
    else if (r < 192) { dst = kls + (r - 64) * 66; grow = jb + (r - 64); sel = 1; }
    else { dst = vls + (r - 192) * 66; grow = jb + (r - 192); sel = 2; }
    if (grow < 0) {
      for (int t = 0; t < 32; ++t) ((unsigned*)dst)[t] = 0u;
    } else {
      const unsigned* src = (const unsigned*)(qkv + ((size_t)(b * Tt + grow)) * C3 + sel * 1024 + h * 64);
      for (int t = 0; t < 32; ++t) ((unsigned*)dst)[t] = src[t];
    }
  }
  __syncthreads();

  const int w = tid >> 6, lane = tid & 63;
  for (int rr = 0; rr < 16; ++rr) {
    const int i = i0 + (w << 4) + rr;
    const int io = i - i0;
    const int ja = i - 64 + lane;           // key for this lane
    const unsigned* qrow = (const unsigned*)(qls + io * 66);
    const unsigned* krow = (const unsigned*)(kls + (size_t)(io + lane) * 66);
    const unsigned* kerow = (const unsigned*)(kls + (size_t)(io + 64) * 66);  // key j=i
    float sa = 0.f, se = 0.f;
#pragma unroll 8
    for (int t = 0; t < 32; ++t) {
      unsigned qq = qrow[t];
      float q0 = bf2f((unsigned short)qq), q1 = bf2f((unsigned short)(qq >> 16));
      unsigned kk = krow[t];
      sa = fmaf(q0, bf2f((unsigned short)kk), sa);
      sa = fmaf(q1, bf2f((unsigned short)(kk >> 16)), sa);
      unsigned ke = kerow[t];
      se = fmaf(q0, bf2f((unsigned short)ke), se);
      se = fmaf(q1, bf2f((unsigned short)(ke >> 16)), se);
    }
    if (ja < 0) sa = -1e30f;
    float m = sa;
    m = fmaxf(m, __shfl_xor(m, 1));
    m = fmaxf(m, __shfl_xor(m, 2));
    m = fmaxf(m, __shfl_xor(m, 4));
    m = fmaxf(m, __shfl_xor(m, 8));
    m = fmaxf(m, __shfl_xor(m, 16));
    m = fmaxf(m, __shfl_xor(m, 32));
    m = fmaxf(m, se);  // se identical on all lanes
    float pa = __expf(sa - m);
    float pe = __expf(se - m);
    float sum = pa;
    sum += __shfl_xor(sum, 1);
    sum += __shfl_xor(sum, 2);
    sum += __shfl_xor(sum, 4);
    sum += __shfl_xor(sum, 8);
    sum += __shfl_xor(sum, 16);
    sum += __shfl_xor(sum, 32);
    sum += pe;
    float rl = 1.0f / sum;
    pls[w][lane] = pa * rl;
    if (lane == 0) pls[w][64] = pe * rl;
    // PV: lane owns output dim d = lane; keys are idx = io + t, t=0..64
    float y = 0.f;
#pragma unroll 4
    for (int t = 0; t <= 64; ++t)
      y = fmaf(pls[w][t], bf2f(vls[(size_t)(io + t) * 66 + lane]), y);
    yh[((size_t)(b * Tt + i)) * 1024 + h * 64 + lane] = f2bf(y);
  }
}

// ============================ host ============================
extern "C" void kernel_launch(void* const* d_in, const int* in_sizes, int n_in,
                              void* d_out, int out_size, void* d_ws, size_t ws_size,
                              hipStream_t stream) {
  const float* x = (const float*)d_in[0];
  const float* Wa = (const float*)d_in[1];
  const float* Wp = (const float*)d_in[2];

  float* out = (float*)d_out;
  float* y_out = out;                               // [4,1024,1024]
  float* att = out + (size_t)4194304;               // [4,16,1024,1024]
  float* astd = out + (size_t)71303168;             // [16,1024,1024]

  // d_ws scratch: qkv bf16 | y_heads bf16 | WtP bf16   (35.7 MB)
  char* ws = (char*)d_ws;
  unsigned short* qkv = (unsigned short*)ws;                 // 25165824 B
  unsigned short* yh = (unsigned short*)(ws + 25165824);     // 8388608 B
  unsigned short* WtP = (unsigned short*)(ws + 33554432);    // 2097152 B

  // park WtA + x_bf16 inside the y output region (dead until final GEMM writes y)
  char* yreg = (char*)d_out;
  unsigned short* WtA = (unsigned short*)yreg;               // 6291456 B
  unsigned short* xbf = (unsigned short*)(yreg + 6291456);   // 8388608 B

  k_convert<<<4096, 256, 0, stream>>>(x, xbf, 1048576);
  k_transconv<<<dim3(96, 32), 256, 0, stream>>>(Wa, WtA, 1024, 3072);
  k_transconv<<<dim3(32, 32), 256, 0, stream>>>(Wp, WtP, 1024, 1024);
  // qkv = x @ W_attn  (q pre-scaled by 1/8), bf16 out
  k_gemm_bt<1, 1><<<dim3(32, 24), 256, 0, stream>>>(xbf, WtA, qkv, 4096, 3072, 1024);
  // fused stats + att + astd
  k_att<<<dim3(32, 16), 256, 0, stream>>>(qkv, att, astd);
  k_bandy<<<1024, 256, 0, stream>>>(qkv, yh);
  // y = y_heads @ W_proj, fp32 out (overwrites the WtA/xbf scratch in-place)
  k_gemm_bt<0, 0><<<dim3(32, 8), 256, 0, stream>>>(yh, WtP, y_out, 4096, 1024, 1024);
}

// Round 6
// 295.586 us; speedup vs baseline: 1.5217x; 1.0473x over previous
//
#include <hip/hip_runtime.h>
#include <hip/hip_bf16.h>
#include <stdint.h>

// Problem constants
#define Bb 4
#define Tt 1024
#define Hh 16
#define HD 64
#define C3 3072
#define WIN 64  // MEMORY

typedef __bf16 bf16x8 __attribute__((ext_vector_type(8)));
typedef float f32x4 __attribute__((ext_vector_type(4)));

#define MFMA16(a, b, c) __builtin_amdgcn_mfma_f32_16x16x32_bf16((a), (b), (c), 0, 0, 0)

static __device__ __forceinline__ unsigned short f2bf(float f) {
  union { float f; unsigned u; } v; v.f = f;
  unsigned r = (v.u + 0x7FFFu + ((v.u >> 16) & 1u)) >> 16;
  return (unsigned short)r;
}
static __device__ __forceinline__ float bf2f(unsigned short h) {
  union { unsigned u; float f; } v; v.u = ((unsigned)h) << 16;
  return v.f;
}

// ---------------- fused prep: x->bf16 convert + both weight transposes ----------------
__global__ __launch_bounds__(256) void k_prep(const float* __restrict__ x,
                                              const float* __restrict__ Wa,
                                              const float* __restrict__ Wp,
                                              unsigned short* __restrict__ xbf,
                                              unsigned short* __restrict__ WtA,
                                              unsigned short* __restrict__ WtP) {
  __shared__ float tile[32][33];
  const int blk = blockIdx.x;
  const int tid = threadIdx.x;
  if (blk < 4096) {  // convert x (1M float4)
    int i = blk * 256 + tid;
    float4 v = ((const float4*)x)[i];
    ushort4 o;
    o.x = f2bf(v.x); o.y = f2bf(v.y); o.z = f2bf(v.z); o.w = f2bf(v.w);
    ((ushort4*)xbf)[i] = o;
    return;
  }
  const float* Win; unsigned short* Wt; int N, n0, k0;
  if (blk < 7168) { int bb = blk - 4096; Win = Wa; Wt = WtA; N = 3072; n0 = (bb % 96) * 32; k0 = (bb / 96) * 32; }
  else           { int bb = blk - 7168; Win = Wp; Wt = WtP; N = 1024; n0 = (bb % 32) * 32; k0 = (bb / 32) * 32; }
  const int K = 1024;
  int tx = tid & 31, ty = tid >> 5;
  for (int r = ty; r < 32; r += 8)
    tile[r][tx] = Win[(size_t)(k0 + r) * N + n0 + tx];
  __syncthreads();
  for (int r = ty; r < 32; r += 8)
    Wt[(size_t)(n0 + r) * K + k0 + tx] = f2bf(tile[tx][r]);
}

// ------------- bf16 GEMM: C[M][N] = A[M][K] * Bt[N][K]^T  (m97-style 128x128 tile) -------------
template <int BF16_OUT, int SCALEQ>
__global__ __launch_bounds__(256) void k_gemm_bt(const unsigned short* __restrict__ A,
                                                 const unsigned short* __restrict__ Bt,
                                                 void* __restrict__ Cv, int M, int N, int K) {
  __shared__ unsigned short lds[2 * 128 * 32];
  unsigned short* as_ = lds;
  unsigned short* bs_ = lds + 128 * 32;
  const int tid = threadIdx.x;
  const int m0 = blockIdx.x * 128, n0 = blockIdx.y * 128;
  const int w = tid >> 6, lane = tid & 63;
  const int wm = (w >> 1) * 64, wn = (w & 1) * 64;
  const int lrow = lane & 15, lk = lane >> 4;

  f32x4 z = {0.f, 0.f, 0.f, 0.f};
  f32x4 acc[4][4];
#pragma unroll
  for (int i = 0; i < 4; ++i)
#pragma unroll
    for (int j = 0; j < 4; ++j) acc[i][j] = z;

  const int nk = K >> 5;
  for (int kt = 0; kt < nk; ++kt) {
    const int k0 = kt << 5;
    __syncthreads();
#pragma unroll
    for (int p = 0; p < 2; ++p) {
      int seg = tid + p * 256;
      int row = seg >> 2, ks = (seg & 3) << 3;
      __builtin_amdgcn_global_load_lds(
          (__attribute__((address_space(1))) void*)(A + (size_t)(m0 + row) * K + k0 + ks),
          (__attribute__((address_space(3))) void*)(as_ + seg * 8), 16, 0, 0);
      __builtin_amdgcn_global_load_lds(
          (__attribute__((address_space(1))) void*)(Bt + (size_t)(n0 + row) * K + k0 + ks),
          (__attribute__((address_space(3))) void*)(bs_ + seg * 8), 16, 0, 0);
    }
    __syncthreads();
    bf16x8 af[4], bfr[4];
#pragma unroll
    for (int f = 0; f < 4; ++f) {
      af[f] = *(const bf16x8*)(as_ + (wm + f * 16 + lrow) * 32 + lk * 8);
      bfr[f] = *(const bf16x8*)(bs_ + (wn + f * 16 + lrow) * 32 + lk * 8);
    }
#pragma unroll
    for (int i = 0; i < 4; ++i)
#pragma unroll
      for (int j = 0; j < 4; ++j) acc[i][j] = MFMA16(af[i], bfr[j], acc[i][j]);
  }
  // epilogue: D row = (lane>>4)*4+r, col = lane&15
  const int r0 = lk * 4;
#pragma unroll
  for (int i = 0; i < 4; ++i)
#pragma unroll
    for (int j = 0; j < 4; ++j)
#pragma unroll
      for (int r = 0; r < 4; ++r) {
        int gm = m0 + wm + i * 16 + r0 + r;
        int gn = n0 + wn + j * 16 + lrow;
        float v = acc[i][j][r];
        if (SCALEQ) {
          if (gn < 1024) v *= 0.125f;  // fold 1/sqrt(hd) into q
        }
        if (BF16_OUT)
          ((unsigned short*)Cv)[(size_t)gm * N + gn] = f2bf(v);
        else
          ((float*)Cv)[(size_t)gm * N + gn] = v;
      }
}

// ------------- fused att: stats (pass1, wave=batch) + barrier-free pass2 (wave=j-stripe) ----
// grid (32 ti, 16 h); 1 barrier per block. Longest blocks (high ti) launch first.
__global__ __launch_bounds__(256) void k_att(const unsigned short* __restrict__ qkv,
                                             float* __restrict__ att, float* __restrict__ astd) {
  const int ti = 31 - blockIdx.x;  // longest-job-first
  const int h = blockIdx.y;
  const int i0 = ti * 32;
  const int tid = threadIdx.x;
  const int w = tid >> 6, lane = tid & 63;
  const int lrow = lane & 15, lk = lane >> 4;

  __shared__ float smr[4][32][2];   // [batch][row][{m, 1/l}]
  __shared__ float wbuf[4][32][36]; // per-WAVE transpose buffer (same-wave use, no barrier)

  // ---- pass 1: wave = batch (b1 = w), verified per-lane online math ----
  {
    const int b1 = w;
    const size_t qb_ = ((size_t)(b1 * Tt + i0 + lrow)) * C3 + h * 64 + lk * 8;
    bf16x8 q00 = *(const bf16x8*)(qkv + qb_);
    bf16x8 q01 = *(const bf16x8*)(qkv + qb_ + 32);
    bf16x8 q10 = *(const bf16x8*)(qkv + qb_ + (size_t)16 * C3);
    bf16x8 q11 = *(const bf16x8*)(qkv + qb_ + (size_t)16 * C3 + 32);

    float m[2][4], l[2][4];
#pragma unroll
    for (int i2 = 0; i2 < 2; ++i2)
#pragma unroll
      for (int r = 0; r < 4; ++r) { m[i2][r] = -1e30f; l[i2][r] = 0.f; }

    for (int jt = 0; jt <= ti; ++jt) {
      const int j0 = jt * 32;
      const size_t krowa = ((size_t)(b1 * Tt + j0 + lrow)) * C3 + 1024 + h * 64 + lk * 8;
      const size_t krowb = krowa + (size_t)16 * C3;
      bf16x8 k00 = *(const bf16x8*)(qkv + krowa);
      bf16x8 k01 = *(const bf16x8*)(qkv + krowa + 32);
      bf16x8 k10 = *(const bf16x8*)(qkv + krowb);
      bf16x8 k11 = *(const bf16x8*)(qkv + krowb + 32);
      const int ja = j0 + lrow, jb2 = j0 + 16 + lrow;
#pragma unroll
      for (int i2 = 0; i2 < 2; ++i2) {
        bf16x8 qa = i2 ? q10 : q00;
        bf16x8 qb = i2 ? q11 : q01;
        f32x4 sa = {0.f, 0.f, 0.f, 0.f}, sb = {0.f, 0.f, 0.f, 0.f};
        sa = MFMA16(qa, k00, sa);
        sa = MFMA16(qb, k01, sa);
        sb = MFMA16(qa, k10, sb);
        sb = MFMA16(qb, k11, sb);
#pragma unroll
        for (int r = 0; r < 4; ++r) {
          int ig = i0 + i2 * 16 + lk * 4 + r;
          int oka = (ja <= ig), okb = (jb2 <= ig);
          float va = oka ? sa[r] : -1e30f;
          float vb = okb ? sb[r] : -1e30f;
          float mn = fmaxf(m[i2][r], fmaxf(va, vb));
          float pa = oka ? __expf(sa[r] - mn) : 0.f;
          float pb = okb ? __expf(sb[r] - mn) : 0.f;
          l[i2][r] = l[i2][r] * __expf(m[i2][r] - mn) + pa + pb;
          m[i2][r] = mn;
        }
      }
    }
    // butterfly merge across 16-lane lrow groups; lane lrow==0 publishes to LDS
#pragma unroll
    for (int i2 = 0; i2 < 2; ++i2)
#pragma unroll
      for (int r = 0; r < 4; ++r) {
        float mm = m[i2][r], ll = l[i2][r];
#pragma unroll
        for (int d = 1; d <= 8; d <<= 1) {
          float mo = __shfl_xor(mm, d);
          float lo = __shfl_xor(ll, d);
          float mn = fmaxf(mm, mo);
          ll = ll * __expf(mm - mn) + lo * __expf(mo - mn);
          mm = mn;
        }
        if (lrow == 0) {
          int row = i2 * 16 + lk * 4 + r;
          smr[b1][row][0] = mm;
          smr[b1][row][1] = 1.0f / ll;
        }
      }
  }
  __syncthreads();  // the ONLY block barrier

  // ---- q fragments for ALL batches (static indexing only) ----
  bf16x8 qf[4][2][2];
#pragma unroll
  for (int b = 0; b < 4; ++b) {
    const size_t qb_ = ((size_t)(b * Tt + i0 + lrow)) * C3 + h * 64 + lk * 8;
    qf[b][0][0] = *(const bf16x8*)(qkv + qb_);
    qf[b][0][1] = *(const bf16x8*)(qkv + qb_ + 32);
    qf[b][1][0] = *(const bf16x8*)(qkv + qb_ + (size_t)16 * C3);
    qf[b][1][1] = *(const bf16x8*)(qkv + qb_ + (size_t)16 * C3 + 32);
  }

  // ---- pass 2: wave w owns j-tiles w, w+4, ... (all 4 batches); no barriers ----
  const float4 z4 = make_float4(0.f, 0.f, 0.f, 0.f);
  for (int jt = w; jt < 32; jt += 4) {
    const int j0 = jt * 32;
    if (jt > ti) {  // masked region: pure zero streams
#pragma unroll
      for (int b = 0; b < 4; ++b)
#pragma unroll
        for (int q = 0; q < 4; ++q) {
          int f = q * 64 + lane;
          int row = f >> 3, c4 = f & 7;
          *(float4*)&att[(((size_t)(b * Hh + h)) * Tt + i0 + row) * Tt + j0 + c4 * 4] = z4;
        }
#pragma unroll
      for (int q = 0; q < 4; ++q) {
        int f = q * 64 + lane;
        int row = f >> 3, c4 = f & 7;
        *(float4*)&astd[((size_t)h * Tt + i0 + row) * Tt + j0 + c4 * 4] = z4;
      }
      continue;
    }
    float s1[2][2][4], s2[2][2][4];
#pragma unroll
    for (int i2 = 0; i2 < 2; ++i2)
#pragma unroll
      for (int j2 = 0; j2 < 2; ++j2)
#pragma unroll
        for (int r = 0; r < 4; ++r) { s1[i2][j2][r] = 0.f; s2[i2][j2][r] = 0.f; }

#pragma unroll
    for (int b = 0; b < 4; ++b) {
      const size_t krowa = ((size_t)(b * Tt + j0 + lrow)) * C3 + 1024 + h * 64 + lk * 8;
      const size_t krowb = krowa + (size_t)16 * C3;
      bf16x8 k00 = *(const bf16x8*)(qkv + krowa);
      bf16x8 k01 = *(const bf16x8*)(qkv + krowa + 32);
      bf16x8 k10 = *(const bf16x8*)(qkv + krowb);
      bf16x8 k11 = *(const bf16x8*)(qkv + krowb + 32);
#pragma unroll
      for (int i2 = 0; i2 < 2; ++i2) {
        // row stats for this (b,i2): 8 broadcast LDS reads (keeps VGPR pressure down)
        float mm[4], rr[4];
#pragma unroll
        for (int r = 0; r < 4; ++r) {
          int row = i2 * 16 + lk * 4 + r;
          mm[r] = smr[b][row][0];
          rr[r] = smr[b][row][1];
        }
#pragma unroll
        for (int j2 = 0; j2 < 2; ++j2) {
          f32x4 s = {0.f, 0.f, 0.f, 0.f};
          s = MFMA16(qf[b][i2][0], j2 ? k10 : k00, s);
          s = MFMA16(qf[b][i2][1], j2 ? k11 : k01, s);
          const int jg = j0 + j2 * 16 + lrow;
#pragma unroll
          for (int r = 0; r < 4; ++r) {
            int ig = i0 + i2 * 16 + lk * 4 + r;
            float p = (jg <= ig) ? __expf(s[r] - mm[r]) * rr[r] : 0.f;
            wbuf[w][i2 * 16 + lk * 4 + r][j2 * 16 + lrow] = p;
            s1[i2][j2][r] += p;
            s2[i2][j2][r] += p * p;
          }
        }
      }
      // same-wave LDS read-back -> float4 att stores for batch b
#pragma unroll
      for (int q = 0; q < 4; ++q) {
        int f = q * 64 + lane;
        int row = f >> 3, c4 = f & 7;
        float4 v = *(float4*)&wbuf[w][row][c4 * 4];
        *(float4*)&att[(((size_t)(b * Hh + h)) * Tt + i0 + row) * Tt + j0 + c4 * 4] = v;
      }
    }
    // astd: batch values accumulated in-register; transpose via same-wave LDS
#pragma unroll
    for (int i2 = 0; i2 < 2; ++i2)
#pragma unroll
      for (int j2 = 0; j2 < 2; ++j2)
#pragma unroll
        for (int r = 0; r < 4; ++r) {
          float mean = s1[i2][j2][r] * 0.25f;
          float var = (s2[i2][j2][r] - 4.f * mean * mean) * (1.f / 3.f);
          wbuf[w][i2 * 16 + lk * 4 + r][j2 * 16 + lrow] = sqrtf(fmaxf(var, 0.f));
        }
#pragma unroll
    for (int q = 0; q < 4; ++q) {
      int f = q * 64 + lane;
      int row = f >> 3, c4 = f & 7;
      float4 v = *(float4*)&wbuf[w][row][c4 * 4];
      *(float4*)&astd[((size_t)h * Tt + i0 + row) * Tt + j0 + c4 * 4] = v;
    }
  }
}

// ------------- banded (window=64) softmax @ V  ->  y_heads bf16 [B][T][C] -------------
// (round-1 verbatim, known-good)
__global__ __launch_bounds__(256) void k_bandy(const unsigned short* __restrict__ qkv,
                                               unsigned short* __restrict__ yh) {
  __shared__ unsigned short qls[64 * 66];
  __shared__ unsigned short kls[128 * 66];
  __shared__ unsigned short vls[128 * 66];
  __shared__ float pls[4][80];

  int blk = blockIdx.x;
  int it = blk & 15, h = (blk >> 4) & 15, b = blk >> 8;
  int i0 = it * 64;
  int jb = i0 - 64;
  int tid = threadIdx.x;

  // stage q rows [i0, i0+63], k/v rows [i0-64, i0+63] (row<0 -> zeros)
  for (int r = tid; r < 320; r += 256) {
    unsigned short* dst;
    int grow, sel;
    if (r < 64) { dst = qls + r * 66; grow = i0 + r; sel = 0; }
    else if (r < 192) { dst = kls + (r - 64) * 66; grow = jb + (r - 64); sel = 1; }
    else { dst = vls + (r - 192) * 66; grow = jb + (r - 192); sel = 2; }
    if (grow < 0) {
      for (int t = 0; t < 32; ++t) ((unsigned*)dst)[t] = 0u;
    } else {
      const unsigned* src = (const unsigned*)(qkv + ((size_t)(b * Tt + grow)) * C3 + sel * 1024 + h * 64);
      for (int t = 0; t < 32; ++t) ((unsigned*)dst)[t] = src[t];
    }
  }
  __syncthreads();

  const int w = tid >> 6, lane = tid & 63;
  for (int rr = 0; rr < 16; ++rr) {
    const int i = i0 + (w << 4) + rr;
    const int io = i - i0;
    const int ja = i - 64 + lane;           // key for this lane
    const unsigned* qrow = (const unsigned*)(qls + io * 66);
    const unsigned* krow = (const unsigned*)(kls + (size_t)(io + lane) * 66);
    const unsigned* kerow = (const unsigned*)(kls + (size_t)(io + 64) * 66);  // key j=i
    float sa = 0.f, se = 0.f;
#pragma unroll 8
    for (int t = 0; t < 32; ++t) {
      unsigned qq = qrow[t];
      float q0 = bf2f((unsigned short)qq), q1 = bf2f((unsigned short)(qq >> 16));
      unsigned kk = krow[t];
      sa = fmaf(q0, bf2f((unsigned short)kk), sa);
      sa = fmaf(q1, bf2f((unsigned short)(kk >> 16)), sa);
      unsigned ke = kerow[t];
      se = fmaf(q0, bf2f((unsigned short)ke), se);
      se = fmaf(q1, bf2f((unsigned short)(ke >> 16)), se);
    }
    if (ja < 0) sa = -1e30f;
    float m = sa;
    m = fmaxf(m, __shfl_xor(m, 1));
    m = fmaxf(m, __shfl_xor(m, 2));
    m = fmaxf(m, __shfl_xor(m, 4));
    m = fmaxf(m, __shfl_xor(m, 8));
    m = fmaxf(m, __shfl_xor(m, 16));
    m = fmaxf(m, __shfl_xor(m, 32));
    m = fmaxf(m, se);  // se identical on all lanes
    float pa = __expf(sa - m);
    float pe = __expf(se - m);
    float sum = pa;
    sum += __shfl_xor(sum, 1);
    sum += __shfl_xor(sum, 2);
    sum += __shfl_xor(sum, 4);
    sum += __shfl_xor(sum, 8);
    sum += __shfl_xor(sum, 16);
    sum += __shfl_xor(sum, 32);
    sum += pe;
    float rl = 1.0f / sum;
    pls[w][lane] = pa * rl;
    if (lane == 0) pls[w][64] = pe * rl;
    // PV: lane owns output dim d = lane; keys are idx = io + t, t=0..64
    float y = 0.f;
#pragma unroll 4
    for (int t = 0; t <= 64; ++t)
      y = fmaf(pls[w][t], bf2f(vls[(size_t)(io + t) * 66 + lane]), y);
    yh[((size_t)(b * Tt + i)) * 1024 + h * 64 + lane] = f2bf(y);
  }
}

// ============================ host ============================
extern "C" void kernel_launch(void* const* d_in, const int* in_sizes, int n_in,
                              void* d_out, int out_size, void* d_ws, size_t ws_size,
                              hipStream_t stream) {
  const float* x = (const float*)d_in[0];
  const float* Wa = (const float*)d_in[1];
  const float* Wp = (const float*)d_in[2];

  float* out = (float*)d_out;
  float* y_out = out;                               // [4,1024,1024]
  float* att = out + (size_t)4194304;               // [4,16,1024,1024]
  float* astd = out + (size_t)71303168;             // [16,1024,1024]

  // d_ws scratch: qkv bf16 | y_heads bf16 | WtP bf16   (35.7 MB)
  char* ws = (char*)d_ws;
  unsigned short* qkv = (unsigned short*)ws;                 // 25165824 B
  unsigned short* yh = (unsigned short*)(ws + 25165824);     // 8388608 B
  unsigned short* WtP = (unsigned short*)(ws + 33554432);    // 2097152 B

  // park WtA + x_bf16 inside the y output region (dead until final GEMM writes y)
  char* yreg = (char*)d_out;
  unsigned short* WtA = (unsigned short*)yreg;               // 6291456 B
  unsigned short* xbf = (unsigned short*)(yreg + 6291456);   // 8388608 B

  // fused prep: convert x + transpose both weights (one dispatch)
  k_prep<<<8192, 256, 0, stream>>>(x, Wa, Wp, xbf, WtA, WtP);
  // qkv = x @ W_attn  (q pre-scaled by 1/8), bf16 out
  k_gemm_bt<1, 1><<<dim3(32, 24), 256, 0, stream>>>(xbf, WtA, qkv, 4096, 3072, 1024);
  // fused stats + att + astd (1 barrier per block)
  k_att<<<dim3(32, 16), 256, 0, stream>>>(qkv, att, astd);
  k_bandy<<<1024, 256, 0, stream>>>(qkv, yh);
  // y = y_heads @ W_proj, fp32 out (overwrites the WtA/xbf scratch in-place)
  k_gemm_bt<0, 0><<<dim3(32, 8), 256, 0, stream>>>(yh, WtP, y_out, 4096, 1024, 1024);
}